// Round 4
// baseline (528.906 us; speedup 1.0000x reference)
//
#include <hip/hip_runtime.h>

#define BS 4
#define SEQL 8192
#define EMB 512
#define NH 8
#define HD 64
#define LM 64
#define SEG 128
#define BH (BS*NH)           // 32
#define NCH 16
#define CHS (SEQL/NCH)       // 512
#define QSCALE 0.35355339059327373f  // 64^(-1/4)

typedef unsigned short u16;
typedef __bf16 bf16_t;
typedef __attribute__((ext_vector_type(8))) __bf16 bf16x8;
typedef __attribute__((ext_vector_type(4))) float f32x4;

#define MFMA16(a, b, c) __builtin_amdgcn_mfma_f32_16x16x32_bf16((a), (b), (c), 0, 0, 0)

__device__ __forceinline__ float bf2f(u16 u) {
  return __uint_as_float(((unsigned int)u) << 16);
}
__device__ __forceinline__ u16 f2bf(float f) {
  unsigned int u = __float_as_uint(f);
  u += 0x7fffu + ((u >> 16) & 1u);   // RNE
  return (u16)(u >> 16);
}
__device__ __forceinline__ float load1_any(const void* p, size_t idx, int isf32) {
  return isf32 ? ((const float*)p)[idx] : bf2f(((const u16*)p)[idx]);
}
__device__ __forceinline__ void load4_any(const void* p, size_t idx, int isf32, float* dst) {
  if (isf32) {
    float4 v = *reinterpret_cast<const float4*>((const float*)p + idx);
    dst[0] = v.x; dst[1] = v.y; dst[2] = v.z; dst[3] = v.w;
  } else {
    ushort4 v = *reinterpret_cast<const ushort4*>((const u16*)p + idx);
    dst[0] = bf2f(v.x); dst[1] = bf2f(v.y); dst[2] = bf2f(v.z); dst[3] = bf2f(v.w);
  }
}
// load 8 consecutive source elems as bf16 bit patterns into o[8]
__device__ __forceinline__ void ld8_bf(const void* p, size_t idx, int isf32, u16* o) {
  if (isf32) {
    const float* f = (const float*)p + idx;
    float4 a = *reinterpret_cast<const float4*>(f);
    float4 b = *reinterpret_cast<const float4*>(f + 4);
    o[0] = f2bf(a.x); o[1] = f2bf(a.y); o[2] = f2bf(a.z); o[3] = f2bf(a.w);
    o[4] = f2bf(b.x); o[5] = f2bf(b.y); o[6] = f2bf(b.z); o[7] = f2bf(b.w);
  } else {
    *reinterpret_cast<int4*>(o) = *reinterpret_cast<const int4*>((const u16*)p + idx);
  }
}

// async global->LDS direct copy, 16B per lane; lds must be the wave-uniform
// chunk base (HW adds lane*16), gsrc is per-lane.
__device__ __forceinline__ void async16(const void* g, void* l) {
  __builtin_amdgcn_global_load_lds(
      (const __attribute__((address_space(1))) void*)g,
      (__attribute__((address_space(3))) void*)l, 16, 0, 0);
}

// x-tile register staging (T14 issue-early / write-late)
struct XRegs {
  float4 xf[8];
  int4   xb[4];
};
__device__ __forceinline__ void loadx(const void* x, size_t base, int isf32, XRegs& r) {
  if (isf32) {
    const float* xp = (const float*)x + base;
    #pragma unroll
    for (int u = 0; u < 8; u++) r.xf[u] = *reinterpret_cast<const float4*>(xp + u * 4);
  } else {
    const u16* xp = (const u16*)x + base;
    #pragma unroll
    for (int u = 0; u < 4; u++) r.xb[u] = *reinterpret_cast<const int4*>(xp + u * 8);
  }
}
__device__ __forceinline__ void writea(u16* As, int dst, int sr, int b0u, int isf32, XRegs& r) {
  #pragma unroll
  for (int u = 0; u < 4; u++) {
    u16 tmp[8];
    if (isf32) {
      tmp[0] = f2bf(r.xf[2*u].x); tmp[1] = f2bf(r.xf[2*u].y);
      tmp[2] = f2bf(r.xf[2*u].z); tmp[3] = f2bf(r.xf[2*u].w);
      tmp[4] = f2bf(r.xf[2*u+1].x); tmp[5] = f2bf(r.xf[2*u+1].y);
      tmp[6] = f2bf(r.xf[2*u+1].z); tmp[7] = f2bf(r.xf[2*u+1].w);
    } else {
      *reinterpret_cast<int4*>(tmp) = r.xb[u];
    }
    const int us = (b0u + u) ^ (sr & 7);
    *reinterpret_cast<int4*>(&As[dst * 8192 + sr * 64 + us * 8]) =
        *reinterpret_cast<int4*>(tmp);
  }
}

// ------------------------------------------------------------- dtype probe
__global__ __launch_bounds__(256) void probe_kernel(const void* x, int* flag) {
  __shared__ int cnt;
  if (threadIdx.x == 0) cnt = 0;
  __syncthreads();
  const u16* p = (const u16*)x;
  int c = 0;
  for (int j = 0; j < 16; j++) {
    u16 u = p[(size_t)(threadIdx.x * 16 + j) * 2];
    int e = (u >> 7) & 0xFF;
    if (e >= 134) c++;
  }
  atomicAdd(&cnt, c);
  __syncthreads();
  if (threadIdx.x == 0) flag[0] = (cnt > 256) ? 1 : 0;
}

// ------------------------------------------------------------- weight transposes -> bf16 WT[n][k]
__global__ __launch_bounds__(256) void prep_wt_kernel(
    const void* Wq, const void* Wk, const void* Wv, const void* Wo, const int* flag,
    u16* __restrict__ WqT, u16* __restrict__ WkT, u16* __restrict__ WvT, u16* __restrict__ WoT)
{
  __shared__ u16 Ws[64 * 72];
  const int id = blockIdx.x;
  const int z = id >> 6, tile = id & 63;
  const int k0 = (tile >> 3) * 64, n0 = (tile & 7) * 64;
  const void* W = (z == 0) ? Wq : (z == 1) ? Wk : (z == 2) ? Wv : Wo;
  u16* WT = (z == 0) ? WqT : (z == 1) ? WkT : (z == 2) ? WvT : WoT;
  const int isf32 = flag[0];
  const int t = threadIdx.x;
  const int r = t >> 2, cq = (t & 3) * 16;
  u16 tmp[8];
  #pragma unroll
  for (int u = 0; u < 2; u++) {
    ld8_bf(W, (size_t)(k0 + r) * EMB + n0 + cq + 8 * u, isf32, tmp);
    *reinterpret_cast<int4*>(&Ws[r * 72 + cq + 8 * u]) = *reinterpret_cast<int4*>(tmp);
  }
  __syncthreads();
  const int nn = t >> 2, kq = (t & 3) * 16;
  #pragma unroll
  for (int u = 0; u < 2; u++) {
    u16 o[8];
    #pragma unroll
    for (int j = 0; j < 8; j++) o[j] = Ws[(kq + 8 * u + j) * 72 + nn];
    *reinterpret_cast<int4*>(&WT[(size_t)(n0 + nn) * EMB + k0 + kq + 8 * u]) =
        *reinterpret_cast<int4*>(o);
  }
}

// ------------------------------------------------------------- xmean
__global__ __launch_bounds__(256) void xmean_kernel(const void* x, const int* flag,
                                                    float* __restrict__ xmean) {
  const int bl = blockIdx.x;
  const int t = threadIdx.x;
  const int isf32 = flag[0];
  const int c = t * 2;
  const size_t base = (size_t)bl * SEG * EMB;
  float s0 = 0.f, s1 = 0.f;
  for (int r = 0; r < SEG; r++) {
    size_t idx = base + (size_t)r * EMB + c;
    if (isf32) {
      float2 v = *reinterpret_cast<const float2*>((const float*)x + idx);
      s0 += v.x; s1 += v.y;
    } else {
      ushort2 v = *reinterpret_cast<const ushort2*>((const u16*)x + idx);
      s0 += bf2f(v.x); s1 += bf2f(v.y);
    }
  }
  xmean[(size_t)bl * EMB + c]     = s0 * (1.0f / SEG);
  xmean[(size_t)bl * EMB + c + 1] = s1 * (1.0f / SEG);
}

// ------------------------------------------------------------- landmark projections (fp32 + bf16 copies)
__global__ __launch_bounds__(256) void lm_proj_kernel(
    const float* __restrict__ xmean,
    const void* Wq, const void* bq, const void* Wk, const void* bk,
    const int* flag, float* __restrict__ qL, float* __restrict__ kL,
    u16* __restrict__ qLb, u16* __restrict__ kLb)
{
  __shared__ float As[64 * 17];
  __shared__ float Bs[16 * 64];
  const int t = threadIdx.x;
  const int m0 = blockIdx.x * 64, n0 = blockIdx.y * 64, z = blockIdx.z;
  const void* W    = z ? Wk : Wq;
  const void* bias = z ? bk : bq;
  float* dst       = z ? kL : qL;
  u16*   dstb      = z ? kLb : qLb;
  const int isf32 = flag[0];
  const int tx = t & 15, ty = t >> 4;
  const int arow = t >> 2, akk = (t & 3) << 2;
  const int brow = t >> 4, bcol = (t & 15) << 2;
  float acc[4][4] = {};
  for (int k0 = 0; k0 < EMB; k0 += 16) {
    float4 av = *reinterpret_cast<const float4*>(xmean + (size_t)(m0 + arow) * EMB + k0 + akk);
    As[arow * 17 + akk + 0] = av.x;
    As[arow * 17 + akk + 1] = av.y;
    As[arow * 17 + akk + 2] = av.z;
    As[arow * 17 + akk + 3] = av.w;
    load4_any(W, (size_t)(k0 + brow) * EMB + n0 + bcol, isf32, &Bs[brow * 64 + bcol]);
    __syncthreads();
    #pragma unroll
    for (int kk = 0; kk < 16; kk++) {
      float a[4], b[4];
      #pragma unroll
      for (int i = 0; i < 4; i++) a[i] = As[(ty * 4 + i) * 17 + kk];
      #pragma unroll
      for (int j = 0; j < 4; j++) b[j] = Bs[kk * 64 + tx * 4 + j];
      #pragma unroll
      for (int i = 0; i < 4; i++)
        #pragma unroll
        for (int j = 0; j < 4; j++)
          acc[i][j] = fmaf(a[i], b[j], acc[i][j]);
    }
    __syncthreads();
  }
  #pragma unroll
  for (int i = 0; i < 4; i++) {
    int m = m0 + ty * 4 + i;
    int b = m >> 6, l = m & 63;
    #pragma unroll
    for (int j = 0; j < 4; j++) {
      int n = n0 + tx * 4 + j;
      int h = n >> 6, d = n & 63;
      float c = (acc[i][j] + load1_any(bias, n, isf32)) * QSCALE;
      size_t idx = (size_t)((b * NH + h) * LM + l) * HD + d;
      dst[idx] = c;
      dstb[idx] = f2bf(c);
    }
  }
}

// ------------------------------------------------------------- fused MFMA QKV projection v4
// T3-minimum pipeline: double-buffered As/Bs (80KB, 2 blocks/CU). Per k-tile:
// issue x(t+1) reg loads + glds B(t+1) -> [cur^1] FIRST, compute 48 MFMA from
// [cur], then cvt+ds_write A(t+1) (write-late), ONE __syncthreads (vmcnt drain
// waits loads issued a full compute-phase earlier). As: XOR-unit-swizzled
// linear [128][64]; Bs: pre-swizzled glds source (as R3).
__global__ __launch_bounds__(256, 2) void proj_qkv_fused_kernel(
    const void* x, const u16* __restrict__ WqT, const u16* __restrict__ WkT,
    const u16* __restrict__ WvT,
    const void* bq, const void* bk, const void* bv, const int* flag,
    u16* __restrict__ Qb, u16* __restrict__ Kb, u16* __restrict__ VbT)
{
  __shared__ u16 smem[2 * 128 * 64 + 2 * 3 * 64 * 64];   // 32KB A + 48KB B = 80KB
  u16* As = smem;                    // [2][128][64], unit-XOR swizzled
  u16* Bs = smem + 2 * 128 * 64;     // [2][3][64][64], unit-XOR swizzled
  const int t = threadIdx.x;
  const int orig = blockIdx.x;                    // XCD = orig & 7
  const int swz  = (orig & 7) * 256 + (orig >> 3);
  const int h    = swz & 7;
  const int m0   = (swz >> 3) * 128;
  const int n0   = h * 64;
  const int isf32 = flag[0];
  const int w = t >> 6, lane = t & 63, q = lane >> 4, c = lane & 15;
  const int wm = (w >> 1) * 64, wn = (w & 1) * 32;
  const int sr = t >> 1, b0u = (t & 1) * 4;         // A staging coords
  const int brow8 = lane >> 3;                       // B glds row in 8-row chunk
  const int bsw   = ((lane & 7) ^ brow8) * 8;        // pre-swizzled source col

  f32x4 acc[3][4][2];
  f32x4 z4 = {0.f, 0.f, 0.f, 0.f};
  #pragma unroll
  for (int z = 0; z < 3; z++)
    #pragma unroll
    for (int mi = 0; mi < 4; mi++) { acc[z][mi][0] = z4; acc[z][mi][1] = z4; }

  XRegs xr;
  const size_t xrow = (size_t)(m0 + sr) * EMB + b0u * 8;

  // ---- prologue: tile 0
  loadx(x, xrow + 0, isf32, xr);
  #pragma unroll
  for (int u = 0; u < 6; u++) {
    int cb = u * 4 + w, z = cb >> 3, r8 = cb & 7;
    const u16* Wt = (z == 0) ? WqT : (z == 1) ? WkT : WvT;
    async16(&Wt[(size_t)(n0 + r8 * 8 + brow8) * EMB + 0 + bsw],
            &Bs[0 * 12288 + z * 4096 + r8 * 512]);
  }
  writea(As, 0, sr, b0u, isf32, xr);
  __syncthreads();

  for (int tt = 0; tt < 8; tt++) {
    const int cur = tt & 1;
    if (tt < 7) {
      const int k1 = (tt + 1) * 64;
      loadx(x, xrow + k1, isf32, xr);
      #pragma unroll
      for (int u = 0; u < 6; u++) {
        int cb = u * 4 + w, z = cb >> 3, r8 = cb & 7;
        const u16* Wt = (z == 0) ? WqT : (z == 1) ? WkT : WvT;
        async16(&Wt[(size_t)(n0 + r8 * 8 + brow8) * EMB + k1 + bsw],
                &Bs[(cur ^ 1) * 12288 + z * 4096 + r8 * 512]);
      }
    }
    #pragma unroll
    for (int kk = 0; kk < 64; kk += 32) {
      const int u0 = ((((kk >> 3) + q) ^ (c & 7))) * 8;   // de-swizzle unit
      bf16x8 af[4];
      #pragma unroll
      for (int mi = 0; mi < 4; mi++)
        af[mi] = *reinterpret_cast<const bf16x8*>(
            &As[cur * 8192 + (wm + mi * 16 + c) * 64 + u0]);
      #pragma unroll
      for (int z = 0; z < 3; z++) {
        bf16x8 b0v = *reinterpret_cast<const bf16x8*>(
            &Bs[cur * 12288 + z * 4096 + (wn + c) * 64 + u0]);
        bf16x8 b1v = *reinterpret_cast<const bf16x8*>(
            &Bs[cur * 12288 + z * 4096 + (wn + 16 + c) * 64 + u0]);
        #pragma unroll
        for (int mi = 0; mi < 4; mi++) {
          acc[z][mi][0] = MFMA16(af[mi], b0v, acc[z][mi][0]);
          acc[z][mi][1] = MFMA16(af[mi], b1v, acc[z][mi][1]);
        }
      }
    }
    if (tt < 7) writea(As, cur ^ 1, sr, b0u, isf32, xr);
    __syncthreads();
  }

  float bb[3][2];
  #pragma unroll
  for (int z = 0; z < 3; z++) {
    const void* bias = (z == 0) ? bq : (z == 1) ? bk : bv;
    bb[z][0] = load1_any(bias, n0 + wn + c, isf32);
    bb[z][1] = load1_any(bias, n0 + wn + 16 + c, isf32);
  }
  const int b = m0 >> 13, s0t = m0 & (SEQL - 1);

  // Q, K: [bh][s][d], scaled
  #pragma unroll
  for (int z = 0; z < 2; z++) {
    u16* dst = z ? Kb : Qb;
    #pragma unroll
    for (int mi = 0; mi < 4; mi++)
      #pragma unroll
      for (int i = 0; i < 4; i++) {
        int s = s0t + wm + mi * 16 + q * 4 + i;
        size_t rowb = ((size_t)((b * NH + h) * SEQL + s)) * HD;
        dst[rowb + wn + c]      = f2bf((acc[z][mi][0][i] + bb[z][0]) * QSCALE);
        dst[rowb + wn + 16 + c] = f2bf((acc[z][mi][1][i] + bb[z][1]) * QSCALE);
      }
  }

  // V: transpose through LDS -> VbT [bh][d][s] (reuses As region, 8704 < 16384)
  __syncthreads();
  #pragma unroll
  for (int mi = 0; mi < 4; mi++)
    #pragma unroll
    for (int i = 0; i < 4; i++) {
      int ml = wm + mi * 16 + q * 4 + i;
      smem[(wn + c) * 136 + ml]      = f2bf(acc[2][mi][0][i] + bb[2][0]);
      smem[(wn + 16 + c) * 136 + ml] = f2bf(acc[2][mi][1][i] + bb[2][1]);
    }
  __syncthreads();
  const int nl = t >> 2, cq2 = (t & 3) * 32;
  #pragma unroll
  for (int u = 0; u < 4; u++)
    *reinterpret_cast<int4*>(&VbT[((size_t)((b * NH + h) * HD + nl)) * SEQL + s0t + cq2 + 8 * u]) =
        *reinterpret_cast<int4*>(&smem[nl * 136 + cq2 + 8 * u]);
}

// ------------------------------------------------------------- kernel_2 softmax + colsums (fp32)
__global__ __launch_bounds__(256) void k2_softmax_kernel(
    const float* __restrict__ qL, const float* __restrict__ kL,
    float* __restrict__ K2, float* __restrict__ cs)
{
  __shared__ float qs[64 * 65], ks[64 * 65], ps[64 * 65];
  const int t = threadIdx.x, bh = blockIdx.x;
  const int r = t >> 2, cb = (t & 3) << 4;
  #pragma unroll
  for (int i = 0; i < 16; i++) {
    qs[r * 65 + cb + i] = qL[((size_t)bh * LM + r) * HD + cb + i];
    ks[r * 65 + cb + i] = kL[((size_t)bh * LM + r) * HD + cb + i];
  }
  __syncthreads();
  float lg[16] = {};
  for (int d = 0; d < HD; d++) {
    float a = qs[r * 65 + d];
    #pragma unroll
    for (int i = 0; i < 16; i++) lg[i] = fmaf(a, ks[(cb + i) * 65 + d], lg[i]);
  }
  float m = lg[0];
  #pragma unroll
  for (int i = 1; i < 16; i++) m = fmaxf(m, lg[i]);
  m = fmaxf(m, __shfl_xor(m, 1));
  m = fmaxf(m, __shfl_xor(m, 2));
  float s = 0.f;
  #pragma unroll
  for (int i = 0; i < 16; i++) { lg[i] = __expf(lg[i] - m); s += lg[i]; }
  s += __shfl_xor(s, 1);
  s += __shfl_xor(s, 2);
  const float inv = 1.0f / s;
  #pragma unroll
  for (int i = 0; i < 16; i++) {
    float p = lg[i] * inv;
    ps[r * 65 + cb + i] = p;
    K2[((size_t)bh * LM + r) * LM + cb + i] = p;
  }
  __syncthreads();
  if (t < 64) {
    float c = 0.f;
    for (int rr = 0; rr < 64; rr++) c += ps[rr * 65 + t];
    cs[bh * LM + t] = c;
  }
}

// ------------------------------------------------------------- Newton-Schulz inverse, split-bf16 MFMA
__device__ __forceinline__ void mm_split(const u16* Ah, const u16* Al,
                                         const u16* Bh, const u16* Bl,
                                         int w, int lane, f32x4* out)
{
  const int q = lane >> 4, c = lane & 15;
  bf16x8 ah[2], al[2];
  #pragma unroll
  for (int k2 = 0; k2 < 2; k2++) {
    ah[k2] = *reinterpret_cast<const bf16x8*>(&Ah[(w * 16 + c) * 72 + k2 * 32 + q * 8]);
    al[k2] = *reinterpret_cast<const bf16x8*>(&Al[(w * 16 + c) * 72 + k2 * 32 + q * 8]);
  }
  #pragma unroll
  for (int nb = 0; nb < 4; nb++) {
    f32x4 acc = {0.f, 0.f, 0.f, 0.f};
    #pragma unroll
    for (int k2 = 0; k2 < 2; k2++) {
      bf16x8 bh_ = *reinterpret_cast<const bf16x8*>(&Bh[(nb * 16 + c) * 72 + k2 * 32 + q * 8]);
      bf16x8 bl_ = *reinterpret_cast<const bf16x8*>(&Bl[(nb * 16 + c) * 72 + k2 * 32 + q * 8]);
      acc = MFMA16(ah[k2], bh_, acc);
      acc = MFMA16(ah[k2], bl_, acc);
      acc = MFMA16(al[k2], bh_, acc);
    }
    out[nb] = acc;
  }
}

__global__ __launch_bounds__(256) void ns_inverse_kernel(
    const float* __restrict__ K2, const float* __restrict__ cs,
    float* __restrict__ Vi)
{
  __shared__ u16 K2h[64 * 72], K2l[64 * 72];   // K2, A-form [m][k]
  __shared__ u16 VAh[64 * 72], VAl[64 * 72];   // V,  A-form [m][k]
  __shared__ u16 VTh[64 * 72], VTl[64 * 72];   // V^T, B-form [n][k]
  __shared__ u16 KVh[64 * 72], KVl[64 * 72];   // KV, A-form
  __shared__ u16 Th [64 * 72], Tl [64 * 72];   // (cI - X)^T, B-form
  __shared__ float red[256];
  const int t = threadIdx.x, bh = blockIdx.x;
  const int w = t >> 6, lane = t & 63, q = lane >> 4, c = lane & 15;

  float m = -1e30f;
  for (int i = t; i < BH * LM; i += 256) m = fmaxf(m, cs[i]);
  red[t] = m;
  __syncthreads();
  for (int off = 128; off; off >>= 1) {
    if (t < off) red[t] = fmaxf(red[t], red[t + off]);
    __syncthreads();
  }
  const float ginv = 1.0f / red[0];
  __syncthreads();

  {
    const int r = t >> 2, cb = (t & 3) << 4;
    #pragma unroll
    for (int i = 0; i < 16; i++) {
      float v = K2[((size_t)bh * LM + r) * LM + cb + i];
      u16 h1 = f2bf(v);
      K2h[r * 72 + cb + i] = h1;
      K2l[r * 72 + cb + i] = f2bf(v - bf2f(h1));
      float sv = v * ginv;
      u16 h2 = f2bf(sv);
      u16 l2 = f2bf(sv - bf2f(h2));
      VTh[r * 72 + cb + i] = h2;
      VTl[r * 72 + cb + i] = l2;
      VAh[(cb + i) * 72 + r] = h2;
      VAl[(cb + i) * 72 + r] = l2;
    }
  }
  __syncthreads();

  f32x4 o[4];
  for (int it = 0; it < 6; it++) {
    mm_split(K2h, K2l, VTh, VTl, w, lane, o);
    __syncthreads();
    #pragma unroll
    for (int nb = 0; nb < 4; nb++)
      #pragma unroll
      for (int i = 0; i < 4; i++) {
        const int row = w * 16 + q * 4 + i, col = nb * 16 + c;
        const float v = o[nb][i];
        const u16 h1 = f2bf(v);
        KVh[row * 72 + col] = h1;
        KVl[row * 72 + col] = f2bf(v - bf2f(h1));
        const float tv = (row == col ? 7.0f : 0.0f) - v;
        const u16 h2 = f2bf(tv);
        Th[col * 72 + row] = h2;
        Tl[col * 72 + row] = f2bf(tv - bf2f(h2));
      }
    __syncthreads();
    mm_split(KVh, KVl, Th, Tl, w, lane, o);
    __syncthreads();
    #pragma unroll
    for (int nb = 0; nb < 4; nb++)
      #pragma unroll
      for (int i = 0; i < 4; i++) {
        const int row = w * 16 + q * 4 + i, col = nb * 16 + c;
        const float tv = (row == col ? 15.0f : 0.0f) - o[nb][i];
        const u16 h2 = f2bf(tv);
        Th[col * 72 + row] = h2;
        Tl[col * 72 + row] = f2bf(tv - bf2f(h2));
      }
    __syncthreads();
    mm_split(KVh, KVl, Th, Tl, w, lane, o);
    __syncthreads();
    #pragma unroll
    for (int nb = 0; nb < 4; nb++)
      #pragma unroll
      for (int i = 0; i < 4; i++) {
        const int row = w * 16 + q * 4 + i, col = nb * 16 + c;
        const float tv = (row == col ? 13.0f : 0.0f) - o[nb][i];
        const u16 h2 = f2bf(tv);
        Th[col * 72 + row] = h2;
        Tl[col * 72 + row] = f2bf(tv - bf2f(h2));
      }
    __syncthreads();
    mm_split(VAh, VAl, Th, Tl, w, lane, o);
    __syncthreads();
    #pragma unroll
    for (int nb = 0; nb < 4; nb++)
      #pragma unroll
      for (int i = 0; i < 4; i++) {
        const int row = w * 16 + q * 4 + i, col = nb * 16 + c;
        const float v = 0.25f * o[nb][i];
        const u16 h1 = f2bf(v);
        const u16 l1 = f2bf(v - bf2f(h1));
        VAh[row * 72 + col] = h1;
        VAl[row * 72 + col] = l1;
        VTh[col * 72 + row] = h1;
        VTl[col * 72 + row] = l1;
        if (it == 5) Vi[((size_t)bh * LM + row) * LM + col] = v;
      }
    __syncthreads();
  }
}

// ------------------------------------------------------------- MFMA kernel_3 @ v (split-K partials) v2
// T14: next-sub K/V loads issued after the pre-PV barrier (hidden under PV);
// ds_write at sub top. Vs double-buffered (PV reads span the write point);
// Ks/Ps single-buffer safe by barrier ordering. LDS ~75KB -> 2 blocks/CU.
__global__ __launch_bounds__(256) void k3v_kernel(
    const u16* __restrict__ qLb, const u16* __restrict__ Kb, const u16* __restrict__ VbT,
    float* __restrict__ pnum, float* __restrict__ pden)
{
  __shared__ u16 Ks[64 * 72], Vs[2][64 * 72], Ps[64 * 72];
  __shared__ float denL[256];
  const int t = threadIdx.x, ch = blockIdx.x, bh = blockIdx.y;
  const int w = t >> 6, lane = t & 63, q = lane >> 4, c = lane & 15;
  const int sr = t >> 2, sp = (t & 3) * 16;

  bf16x8 aq[4][2];
  #pragma unroll
  for (int mi = 0; mi < 4; mi++)
    #pragma unroll
    for (int k2 = 0; k2 < 2; k2++)
      aq[mi][k2] = *reinterpret_cast<const bf16x8*>(
          &qLb[((size_t)bh * LM + mi * 16 + c) * HD + k2 * 32 + q * 8]);

  f32x4 z4 = {0.f, 0.f, 0.f, 0.f};
  f32x4 nacc[4];
  #pragma unroll
  for (int mi = 0; mi < 4; mi++) nacc[mi] = z4;
  float denr[16] = {};

  // prologue loads (sub 0)
  int4 kr0, kr1, vr0, vr1;
  {
    const int s0 = ch * CHS;
    const u16* kp = &Kb[((size_t)bh * SEQL + s0 + sr) * HD + sp];
    const u16* vp = &VbT[((size_t)(bh * HD + sr)) * SEQL + s0 + sp];
    kr0 = *reinterpret_cast<const int4*>(kp);
    kr1 = *reinterpret_cast<const int4*>(kp + 8);
    vr0 = *reinterpret_cast<const int4*>(vp);
    vr1 = *reinterpret_cast<const int4*>(vp + 8);
  }

  for (int sub = 0; sub < 8; sub++) {
    const int cur = sub & 1;
    // stage writes from prefetched regs
    *reinterpret_cast<int4*>(&Ks[sr * 72 + sp])     = kr0;
    *reinterpret_cast<int4*>(&Ks[sr * 72 + sp + 8]) = kr1;
    *reinterpret_cast<int4*>(&Vs[cur][sr * 72 + sp])     = vr0;
    *reinterpret_cast<int4*>(&Vs[cur][sr * 72 + sp + 8]) = vr1;
    __syncthreads();
    f32x4 sacc[4];
    #pragma unroll
    for (int mi = 0; mi < 4; mi++) sacc[mi] = z4;
    bf16x8 bk0 = *reinterpret_cast<const bf16x8*>(&Ks[(w * 16 + c) * 72 + q * 8]);
    bf16x8 bk1 = *reinterpret_cast<const bf16x8*>(&Ks[(w * 16 + c) * 72 + 32 + q * 8]);
    #pragma unroll
    for (int mi = 0; mi < 4; mi++) {
      sacc[mi] = MFMA16(aq[mi][0], bk0, sacc[mi]);
      sacc[mi] = MFMA16(aq[mi][1], bk1, sacc[mi]);
    }
    #pragma unroll
    for (int mi = 0; mi < 4; mi++)
      #pragma unroll
      for (int i = 0; i < 4; i++) {
        float p = __expf(sacc[mi][i]);
        denr[mi * 4 + i] += p;
        Ps[(mi * 16 + q * 4 + i) * 72 + w * 16 + c] = f2bf(p);
      }
    __syncthreads();
    // issue next-sub loads (latency hides under PV)
    if (sub < 7) {
      const int s1 = ch * CHS + (sub + 1) * 64;
      const u16* kp = &Kb[((size_t)bh * SEQL + s1 + sr) * HD + sp];
      const u16* vp = &VbT[((size_t)(bh * HD + sr)) * SEQL + s1 + sp];
      kr0 = *reinterpret_cast<const int4*>(kp);
      kr1 = *reinterpret_cast<const int4*>(kp + 8);
      vr0 = *reinterpret_cast<const int4*>(vp);
      vr1 = *reinterpret_cast<const int4*>(vp + 8);
    }
    #pragma unroll
    for (int k2 = 0; k2 < 2; k2++) {
      bf16x8 bv_ = *reinterpret_cast<const bf16x8*>(&Vs[cur][(w * 16 + c) * 72 + k2 * 32 + q * 8]);
      #pragma unroll
      for (int mi = 0; mi < 4; mi++) {
        bf16x8 ap = *reinterpret_cast<const bf16x8*>(&Ps[(mi * 16 + c) * 72 + k2 * 32 + q * 8]);
        nacc[mi] = MFMA16(ap, bv_, nacc[mi]);
      }
    }
  }
  #pragma unroll
  for (int mi = 0; mi < 4; mi++)
    #pragma unroll
    for (int i = 0; i < 4; i++)
      pnum[(((size_t)bh * NCH + ch) * LM + mi * 16 + q * 4 + i) * HD + w * 16 + c] = nacc[mi][i];
  #pragma unroll
  for (int v = 0; v < 16; v++) {
    denr[v] += __shfl_xor(denr[v], 1);
    denr[v] += __shfl_xor(denr[v], 2);
    denr[v] += __shfl_xor(denr[v], 4);
    denr[v] += __shfl_xor(denr[v], 8);
  }
  if (c == 0) {
    #pragma unroll
    for (int mi = 0; mi < 4; mi++)
      #pragma unroll
      for (int i = 0; i < 4; i++)
        denL[w * 64 + mi * 16 + q * 4 + i] = denr[mi * 4 + i];
  }
  __syncthreads();
  if (t < 64)
    pden[((size_t)bh * NCH + ch) * LM + t] = denL[t] + denL[64 + t] + denL[128 + t] + denL[192 + t];
}

// ------------------------------------------------------------- reduce partials; W2T = (Vi @ normalize(k3 v))^T bf16
__global__ __launch_bounds__(256) void k3v_w2_kernel(
    const float* __restrict__ pnum, const float* __restrict__ pden,
    const float* __restrict__ Vi, u16* __restrict__ W2T)
{
  __shared__ float Vs[64 * 65], Ms[64 * 65], den[64];
  const int t = threadIdx.x, bh = blockIdx.x;
  const int r = t >> 2, cb = (t & 3) << 4;
  #pragma unroll
  for (int i = 0; i < 16; i++) Vs[r * 65 + cb + i] = Vi[((size_t)bh * LM + r) * LM + cb + i];
  float acc[16] = {};
  for (int ch = 0; ch < NCH; ch++) {
    const float* p = pnum + (((size_t)bh * NCH + ch) * LM + r) * HD + cb;
    #pragma unroll
    for (int i = 0; i < 16; i++) acc[i] += p[i];
  }
  if ((t & 3) == 0) {
    float d = 0.f;
    for (int ch = 0; ch < NCH; ch++) d += pden[((size_t)bh * NCH + ch) * LM + r];
    den[r] = d;
  }
  __syncthreads();
  const float dinv = 1.0f / den[r];
  #pragma unroll
  for (int i = 0; i < 16; i++) Ms[r * 65 + cb + i] = acc[i] * dinv;
  __syncthreads();
  float o[16] = {};
  for (int k = 0; k < 64; k++) {
    float a = Vs[r * 65 + k];
    #pragma unroll
    for (int i = 0; i < 16; i++) o[i] = fmaf(a, Ms[k * 65 + cb + i], o[i]);
  }
  #pragma unroll
  for (int i = 0; i < 16; i++)
    W2T[((size_t)bh * HD + cb + i) * LM + r] = f2bf(o[i]);
}

// ------------------------------------------------------------- MFMA kernel_1 softmax @ W2
__global__ __launch_bounds__(256) void final_kernel(
    const u16* __restrict__ Qb, const u16* __restrict__ kLb, const u16* __restrict__ W2T,
    u16* __restrict__ pre)
{
  __shared__ u16 Ps[64 * 72];
  __shared__ float mxL[256], smL[256];
  const int t = threadIdx.x, st = blockIdx.x, bh = blockIdx.y;
  const int w = t >> 6, lane = t & 63, q = lane >> 4, c = lane & 15;
  const int sb = st * 64;

  bf16x8 aq[4][2], bkL[2], bw2[2];
  #pragma unroll
  for (int mi = 0; mi < 4; mi++)
    #pragma unroll
    for (int k2 = 0; k2 < 2; k2++)
      aq[mi][k2] = *reinterpret_cast<const bf16x8*>(
          &Qb[((size_t)bh * SEQL + sb + mi * 16 + c) * HD + k2 * 32 + q * 8]);
  #pragma unroll
  for (int k2 = 0; k2 < 2; k2++) {
    bkL[k2] = *reinterpret_cast<const bf16x8*>(
        &kLb[((size_t)bh * LM + w * 16 + c) * HD + k2 * 32 + q * 8]);
    bw2[k2] = *reinterpret_cast<const bf16x8*>(
        &W2T[((size_t)bh * HD + w * 16 + c) * LM + k2 * 32 + q * 8]);
  }

  f32x4 z4 = {0.f, 0.f, 0.f, 0.f};
  f32x4 sacc[4];
  #pragma unroll
  for (int mi = 0; mi < 4; mi++) sacc[mi] = z4;
  #pragma unroll
  for (int k2 = 0; k2 < 2; k2++)
    #pragma unroll
    for (int mi = 0; mi < 4; mi++)
      sacc[mi] = MFMA16(aq[mi][k2], bkL[k2], sacc[mi]);

  float mx[16];
  #pragma unroll
  for (int v = 0; v < 16; v++) {
    mx[v] = sacc[v >> 2][v & 3];
    mx[v] = fmaxf(mx[v], __shfl_xor(mx[v], 1));
    mx[v] = fmaxf(mx[v], __shfl_xor(mx[v], 2));
    mx[v] = fmaxf(mx[v], __shfl_xor(mx[v], 4));
    mx[v] = fmaxf(mx[v], __shfl_xor(mx[v], 8));
  }
  if (c == 0) {
    #pragma unroll
    for (int mi = 0; mi < 4; mi++)
      #pragma unroll
      for (int i = 0; i < 4; i++)
        mxL[w * 64 + mi * 16 + q * 4 + i] = mx[mi * 4 + i];
  }
  __syncthreads();
  float p[16], dn[16];
  #pragma unroll
  for (int mi = 0; mi < 4; mi++)
    #pragma unroll
    for (int i = 0; i < 4; i++) {
      int row = mi * 16 + q * 4 + i;
      float M = fmaxf(fmaxf(mxL[row], mxL[64 + row]), fmaxf(mxL[128 + row], mxL[192 + row]));
      float pp = __expf(sacc[mi][i] - M);
      p[mi * 4 + i] = pp;
      dn[mi * 4 + i] = pp;
    }
  #pragma unroll
  for (int v = 0; v < 16; v++) {
    dn[v] += __shfl_xor(dn[v], 1);
    dn[v] += __shfl_xor(dn[v], 2);
    dn[v] += __shfl_xor(dn[v], 4);
    dn[v] += __shfl_xor(dn[v], 8);
  }
  if (c == 0) {
    #pragma unroll
    for (int mi = 0; mi < 4; mi++)
      #pragma unroll
      for (int i = 0; i < 4; i++)
        smL[w * 64 + mi * 16 + q * 4 + i] = dn[mi * 4 + i];
  }
  #pragma unroll
  for (int mi = 0; mi < 4; mi++)
    #pragma unroll
    for (int i = 0; i < 4; i++)
      Ps[(mi * 16 + q * 4 + i) * 72 + w * 16 + c] = f2bf(p[mi * 4 + i]);
  __syncthreads();

  f32x4 oacc[4];
  #pragma unroll
  for (int mi = 0; mi < 4; mi++) oacc[mi] = z4;
  #pragma unroll
  for (int k2 = 0; k2 < 2; k2++)
    #pragma unroll
    for (int mi = 0; mi < 4; mi++) {
      bf16x8 ap = *reinterpret_cast<const bf16x8*>(&Ps[(mi * 16 + c) * 72 + k2 * 32 + q * 8]);
      oacc[mi] = MFMA16(ap, bw2[k2], oacc[mi]);
    }
  #pragma unroll
  for (int mi = 0; mi < 4; mi++)
    #pragma unroll
    for (int i = 0; i < 4; i++) {
      int row = mi * 16 + q * 4 + i;
      float den = smL[row] + smL[64 + row] + smL[128 + row] + smL[192 + row];
      float v = oacc[mi][i] / den;
      pre[((size_t)((bh >> 3) * SEQL + sb + row)) * EMB + (bh & 7) * HD + w * 16 + c] = f2bf(v);
    }
}

// ------------------------------------------------------------- MFMA out = pre @ Wo + bo v2
// T3-minimum: double-buffered glds staging (64KB, 2 blocks/CU); glds(t+1)
// issued before compute(t); one barrier per k-tile.
__global__ __launch_bounds__(256, 2) void out_proj_kernel(
    const u16* __restrict__ pre, const u16* __restrict__ WoT, const void* bo,
    const int* flag, void* out)
{
  __shared__ u16 As[2 * 128 * 64];   // linear rows, unit-swizzled cols
  __shared__ u16 Bs[2 * 128 * 64];
  const int t = threadIdx.x;
  const int m0 = blockIdx.x * 128, n0 = blockIdx.y * 128;
  const int isf32 = flag[0];
  const int w = t >> 6, lane = t & 63, q = lane >> 4, c = lane & 15;
  const int wm = (w >> 1) * 64, wn = (w & 1) * 64;
  const int row8 = lane >> 3;
  const int colsw = ((lane & 7) ^ row8) * 8;

  f32x4 acc[4][4];
  f32x4 z4 = {0.f, 0.f, 0.f, 0.f};
  #pragma unroll
  for (int mi = 0; mi < 4; mi++)
    #pragma unroll
    for (int ni = 0; ni < 4; ni++) acc[mi][ni] = z4;

  // prologue: tile 0
  #pragma unroll
  for (int u = 0; u < 4; u++) {
    int chA = u * 4 + w;
    async16(&pre[(size_t)(m0 + chA * 8 + row8) * EMB + 0 + colsw], &As[chA * 512]);
    async16(&WoT[(size_t)(n0 + chA * 8 + row8) * EMB + 0 + colsw], &Bs[chA * 512]);
  }
  __syncthreads();

  for (int tt = 0; tt < 8; tt++) {
    const int cur = tt & 1;
    if (tt < 7) {
      const int k1 = (tt + 1) * 64;
      #pragma unroll
      for (int u = 0; u < 4; u++) {
        int chA = u * 4 + w;
        async16(&pre[(size_t)(m0 + chA * 8 + row8) * EMB + k1 + colsw],
                &As[(cur ^ 1) * 8192 + chA * 512]);
        async16(&WoT[(size_t)(n0 + chA * 8 + row8) * EMB + k1 + colsw],
                &Bs[(cur ^ 1) * 8192 + chA * 512]);
      }
    }
    #pragma unroll
    for (int kk = 0; kk < 64; kk += 32) {
      const int u0 = ((((kk >> 3) + q) ^ (c & 7))) * 8;
      bf16x8 af[4], bfv[4];
      #pragma unroll
      for (int mi = 0; mi < 4; mi++)
        af[mi] = *reinterpret_cast<const bf16x8*>(&As[cur * 8192 + (wm + mi * 16 + c) * 64 + u0]);
      #pragma unroll
      for (int ni = 0; ni < 4; ni++)
        bfv[ni] = *reinterpret_cast<const bf16x8*>(&Bs[cur * 8192 + (wn + ni * 16 + c) * 64 + u0]);
      #pragma unroll
      for (int mi = 0; mi < 4; mi++)
        #pragma unroll
        for (int ni = 0; ni < 4; ni++)
          acc[mi][ni] = MFMA16(af[mi], bfv[ni], acc[mi][ni]);
    }
    __syncthreads();
  }
  float bb[4];
  #pragma unroll
  for (int ni = 0; ni < 4; ni++) bb[ni] = load1_any(bo, n0 + wn + ni * 16 + c, isf32);
  #pragma unroll
  for (int mi = 0; mi < 4; mi++)
    #pragma unroll
    for (int i = 0; i < 4; i++) {
      int m = m0 + wm + mi * 16 + q * 4 + i;
      #pragma unroll
      for (int ni = 0; ni < 4; ni++) {
        int n = n0 + wn + ni * 16 + c;
        float v = acc[mi][ni][i] + bb[ni];
        if (isf32) ((float*)out)[(size_t)m * EMB + n] = v;
        else       ((u16*)out)[(size_t)m * EMB + n] = f2bf(v);
      }
    }
}

// ------------------------------------------------------------- launch
extern "C" void kernel_launch(void* const* d_in, const int* in_sizes, int n_in,
                              void* d_out, int out_size, void* d_ws, size_t ws_size,
                              hipStream_t stream)
{
  (void)in_sizes; (void)n_in; (void)out_size; (void)ws_size;
  const void* x  = d_in[0];
  const void* Wq = d_in[1];
  const void* bq = d_in[2];
  const void* Wk = d_in[3];
  const void* bk = d_in[4];
  const void* Wv = d_in[5];
  const void* bv = d_in[6];
  const void* Wo = d_in[7];
  const void* bo = d_in[8];

  float* ws = (float*)d_ws;
  int*   flag  = (int*)ws;                         // 64 floats
  float* xmean = ws + 64;                          // 131072
  float* qL    = xmean + 131072;                   // 131072
  float* kL    = qL + 131072;                      // 131072
  float* K2    = kL + 131072;                      // 131072
  float* cs    = K2 + 131072;                      // 2048
  float* Vi    = cs + 2048;                        // 131072
  float* pnum  = Vi + 131072;                      // 2097152
  float* pden  = pnum + 2097152;                   // 32768
  u16* WqT = (u16*)(pden + 32768);                 // 262144 u16 each
  u16* WkT = WqT + 262144;
  u16* WvT = WkT + 262144;
  u16* WoT = WvT + 262144;
  u16* qLb = WoT + 262144;                         // 131072
  u16* kLb = qLb + 131072;                         // 131072
  u16* W2T = kLb + 131072;                         // 131072
  u16* Qb  = W2T + 131072;                         // 16777216
  u16* Kb  = Qb + 16777216;                        // 16777216
  u16* VbT = Kb + 16777216;                        // 16777216
  u16* pre = Kb;  // alias: Kb dead after k3v_kernel; final runs after k3v_w2

  probe_kernel<<<1, 256, 0, stream>>>(x, flag);
  prep_wt_kernel<<<256, 256, 0, stream>>>(Wq, Wk, Wv, Wo, flag, WqT, WkT, WvT, WoT);
  xmean_kernel<<<BS * LM, 256, 0, stream>>>(x, flag, xmean);
  lm_proj_kernel<<<dim3(4, 8, 2), 256, 0, stream>>>(xmean, Wq, bq, Wk, bk, flag, qL, kL, qLb, kLb);
  proj_qkv_fused_kernel<<<dim3(2048), 256, 0, stream>>>(
      x, WqT, WkT, WvT, bq, bk, bv, flag, Qb, Kb, VbT);
  k2_softmax_kernel<<<BH, 256, 0, stream>>>(qL, kL, K2, cs);
  ns_inverse_kernel<<<BH, 256, 0, stream>>>(K2, cs, Vi);
  k3v_kernel<<<dim3(NCH, BH), 256, 0, stream>>>(qLb, Kb, VbT, pnum, pden);
  k3v_w2_kernel<<<BH, 256, 0, stream>>>(pnum, pden, Vi, W2T);
  final_kernel<<<dim3(SEQL / 64, BH), 256, 0, stream>>>(Qb, kLb, W2T, pre);
  out_proj_kernel<<<dim3(256, 4), 256, 0, stream>>>(pre, WoT, bo, flag, d_out);
}

// Round 5
// 433.635 us; speedup vs baseline: 1.2197x; 1.2197x over previous
//
#include <hip/hip_runtime.h>

#define BS 4
#define SEQL 8192
#define EMB 512
#define NH 8
#define HD 64
#define LM 64
#define SEG 128
#define BH (BS*NH)           // 32
#define NCH 16
#define CHS (SEQL/NCH)       // 512
#define QSCALE 0.35355339059327373f  // 64^(-1/4)

typedef unsigned short u16;
typedef __bf16 bf16_t;
typedef __attribute__((ext_vector_type(8))) __bf16 bf16x8;
typedef __attribute__((ext_vector_type(4))) float f32x4;

#define MFMA16(a, b, c) __builtin_amdgcn_mfma_f32_16x16x32_bf16((a), (b), (c), 0, 0, 0)

__device__ __forceinline__ float bf2f(u16 u) {
  return __uint_as_float(((unsigned int)u) << 16);
}
__device__ __forceinline__ u16 f2bf(float f) {
  unsigned int u = __float_as_uint(f);
  u += 0x7fffu + ((u >> 16) & 1u);   // RNE
  return (u16)(u >> 16);
}
__device__ __forceinline__ float load1_any(const void* p, size_t idx, int isf32) {
  return isf32 ? ((const float*)p)[idx] : bf2f(((const u16*)p)[idx]);
}
__device__ __forceinline__ void load4_any(const void* p, size_t idx, int isf32, float* dst) {
  if (isf32) {
    float4 v = *reinterpret_cast<const float4*>((const float*)p + idx);
    dst[0] = v.x; dst[1] = v.y; dst[2] = v.z; dst[3] = v.w;
  } else {
    ushort4 v = *reinterpret_cast<const ushort4*>((const u16*)p + idx);
    dst[0] = bf2f(v.x); dst[1] = bf2f(v.y); dst[2] = bf2f(v.z); dst[3] = bf2f(v.w);
  }
}
// load 8 consecutive source elems as bf16 bit patterns into o[8]
__device__ __forceinline__ void ld8_bf(const void* p, size_t idx, int isf32, u16* o) {
  if (isf32) {
    const float* f = (const float*)p + idx;
    float4 a = *reinterpret_cast<const float4*>(f);
    float4 b = *reinterpret_cast<const float4*>(f + 4);
    o[0] = f2bf(a.x); o[1] = f2bf(a.y); o[2] = f2bf(a.z); o[3] = f2bf(a.w);
    o[4] = f2bf(b.x); o[5] = f2bf(b.y); o[6] = f2bf(b.z); o[7] = f2bf(b.w);
  } else {
    *reinterpret_cast<int4*>(o) = *reinterpret_cast<const int4*>((const u16*)p + idx);
  }
}

// async global->LDS direct copy, 16B per lane; lds must be the wave-uniform
// chunk base (HW adds lane*16), gsrc is per-lane.
__device__ __forceinline__ void async16(const void* g, void* l) {
  __builtin_amdgcn_global_load_lds(
      (const __attribute__((address_space(1))) void*)g,
      (__attribute__((address_space(3))) void*)l, 16, 0, 0);
}

// ------------------------------------------------------------- dtype probe
__global__ __launch_bounds__(256) void probe_kernel(const void* x, int* flag) {
  __shared__ int cnt;
  if (threadIdx.x == 0) cnt = 0;
  __syncthreads();
  const u16* p = (const u16*)x;
  int c = 0;
  for (int j = 0; j < 16; j++) {
    u16 u = p[(size_t)(threadIdx.x * 16 + j) * 2];
    int e = (u >> 7) & 0xFF;
    if (e >= 134) c++;
  }
  atomicAdd(&cnt, c);
  __syncthreads();
  if (threadIdx.x == 0) flag[0] = (cnt > 256) ? 1 : 0;
}

// ------------------------------------------------------------- weight transposes -> bf16 WT[n][k]
__global__ __launch_bounds__(256) void prep_wt_kernel(
    const void* Wq, const void* Wk, const void* Wv, const void* Wo, const int* flag,
    u16* __restrict__ WqT, u16* __restrict__ WkT, u16* __restrict__ WvT, u16* __restrict__ WoT)
{
  __shared__ u16 Ws[64 * 72];
  const int id = blockIdx.x;
  const int z = id >> 6, tile = id & 63;
  const int k0 = (tile >> 3) * 64, n0 = (tile & 7) * 64;
  const void* W = (z == 0) ? Wq : (z == 1) ? Wk : (z == 2) ? Wv : Wo;
  u16* WT = (z == 0) ? WqT : (z == 1) ? WkT : (z == 2) ? WvT : WoT;
  const int isf32 = flag[0];
  const int t = threadIdx.x;
  const int r = t >> 2, cq = (t & 3) * 16;
  u16 tmp[8];
  #pragma unroll
  for (int u = 0; u < 2; u++) {
    ld8_bf(W, (size_t)(k0 + r) * EMB + n0 + cq + 8 * u, isf32, tmp);
    *reinterpret_cast<int4*>(&Ws[r * 72 + cq + 8 * u]) = *reinterpret_cast<int4*>(tmp);
  }
  __syncthreads();
  const int nn = t >> 2, kq = (t & 3) * 16;
  #pragma unroll
  for (int u = 0; u < 2; u++) {
    u16 o[8];
    #pragma unroll
    for (int j = 0; j < 8; j++) o[j] = Ws[(kq + 8 * u + j) * 72 + nn];
    *reinterpret_cast<int4*>(&WT[(size_t)(n0 + nn) * EMB + k0 + kq + 8 * u]) =
        *reinterpret_cast<int4*>(o);
  }
}

// ------------------------------------------------------------- xmean + x->bf16 copy
// Fused: this kernel already streams all of x; also emit xb16 (plain bf16 copy)
// so proj_qkv can stage A via global_load_lds with no per-thread cvt/staging.
__global__ __launch_bounds__(256) void xmean_kernel(const void* x, const int* flag,
                                                    float* __restrict__ xmean,
                                                    u16* __restrict__ xb16) {
  const int bl = blockIdx.x;
  const int t = threadIdx.x;
  const int isf32 = flag[0];
  const int c = t * 2;
  const size_t base = (size_t)bl * SEG * EMB;
  float s0 = 0.f, s1 = 0.f;
  for (int r = 0; r < SEG; r++) {
    size_t idx = base + (size_t)r * EMB + c;
    ushort2 ob;
    if (isf32) {
      float2 v = *reinterpret_cast<const float2*>((const float*)x + idx);
      s0 += v.x; s1 += v.y;
      ob.x = f2bf(v.x); ob.y = f2bf(v.y);
    } else {
      ushort2 v = *reinterpret_cast<const ushort2*>((const u16*)x + idx);
      s0 += bf2f(v.x); s1 += bf2f(v.y);
      ob = v;
    }
    *reinterpret_cast<ushort2*>(&xb16[idx]) = ob;
  }
  xmean[(size_t)bl * EMB + c]     = s0 * (1.0f / SEG);
  xmean[(size_t)bl * EMB + c + 1] = s1 * (1.0f / SEG);
}

// ------------------------------------------------------------- landmark projections (fp32 + bf16 copies)
__global__ __launch_bounds__(256) void lm_proj_kernel(
    const float* __restrict__ xmean,
    const void* Wq, const void* bq, const void* Wk, const void* bk,
    const int* flag, float* __restrict__ qL, float* __restrict__ kL,
    u16* __restrict__ qLb, u16* __restrict__ kLb)
{
  __shared__ float As[64 * 17];
  __shared__ float Bs[16 * 64];
  const int t = threadIdx.x;
  const int m0 = blockIdx.x * 64, n0 = blockIdx.y * 64, z = blockIdx.z;
  const void* W    = z ? Wk : Wq;
  const void* bias = z ? bk : bq;
  float* dst       = z ? kL : qL;
  u16*   dstb      = z ? kLb : qLb;
  const int isf32 = flag[0];
  const int tx = t & 15, ty = t >> 4;
  const int arow = t >> 2, akk = (t & 3) << 2;
  const int brow = t >> 4, bcol = (t & 15) << 2;
  float acc[4][4] = {};
  for (int k0 = 0; k0 < EMB; k0 += 16) {
    float4 av = *reinterpret_cast<const float4*>(xmean + (size_t)(m0 + arow) * EMB + k0 + akk);
    As[arow * 17 + akk + 0] = av.x;
    As[arow * 17 + akk + 1] = av.y;
    As[arow * 17 + akk + 2] = av.z;
    As[arow * 17 + akk + 3] = av.w;
    load4_any(W, (size_t)(k0 + brow) * EMB + n0 + bcol, isf32, &Bs[brow * 64 + bcol]);
    __syncthreads();
    #pragma unroll
    for (int kk = 0; kk < 16; kk++) {
      float a[4], b[4];
      #pragma unroll
      for (int i = 0; i < 4; i++) a[i] = As[(ty * 4 + i) * 17 + kk];
      #pragma unroll
      for (int j = 0; j < 4; j++) b[j] = Bs[kk * 64 + tx * 4 + j];
      #pragma unroll
      for (int i = 0; i < 4; i++)
        #pragma unroll
        for (int j = 0; j < 4; j++)
          acc[i][j] = fmaf(a[i], b[j], acc[i][j]);
    }
    __syncthreads();
  }
  #pragma unroll
  for (int i = 0; i < 4; i++) {
    int m = m0 + ty * 4 + i;
    int b = m >> 6, l = m & 63;
    #pragma unroll
    for (int j = 0; j < 4; j++) {
      int n = n0 + tx * 4 + j;
      int h = n >> 6, d = n & 63;
      float c = (acc[i][j] + load1_any(bias, n, isf32)) * QSCALE;
      size_t idx = (size_t)((b * NH + h) * LM + l) * HD + d;
      dst[idx] = c;
      dstb[idx] = f2bf(c);
    }
  }
}

// ------------------------------------------------------------- fused MFMA QKV projection v5
// Both A (xb16) and B (WT) staged via global_load_lds with pre-swizzled per-lane
// source cols + linear LDS dest (both-sides involution). Double-buffered, ONE
// __syncthreads per k-tile; prefetch for t+1 issued before compute(t) so the
// barrier's vmcnt(0) drain lands after a full MFMA phase. No per-thread arrays.
__global__ __launch_bounds__(256, 2) void proj_qkv_fused_kernel(
    const u16* __restrict__ xb16, const u16* __restrict__ WqT,
    const u16* __restrict__ WkT, const u16* __restrict__ WvT,
    const void* bq, const void* bk, const void* bv, const int* flag,
    u16* __restrict__ Qb, u16* __restrict__ Kb, u16* __restrict__ VbT)
{
  __shared__ u16 smem[2 * 128 * 64 + 2 * 3 * 64 * 64];   // 32KB A + 48KB B = 80KB
  u16* As = smem;                    // [2][16 chunks][512]
  u16* Bs = smem + 2 * 128 * 64;     // [2][3][8 chunks][512]
  const int t = threadIdx.x;
  const int orig = blockIdx.x;                    // XCD = orig & 7
  const int swz  = (orig & 7) * 256 + (orig >> 3);
  const int h    = swz & 7;
  const int m0   = (swz >> 3) * 128;
  const int n0   = h * 64;
  const int isf32 = flag[0];
  const int w = t >> 6, lane = t & 63, q = lane >> 4, c = lane & 15;
  const int wm = (w >> 1) * 64, wn = (w & 1) * 32;
  const int row8 = lane >> 3;                       // glds row within 8-row chunk
  const int csw  = ((lane & 7) ^ row8) * 8;         // pre-swizzled source col

  f32x4 acc[3][4][2];
  f32x4 z4 = {0.f, 0.f, 0.f, 0.f};
  #pragma unroll
  for (int z = 0; z < 3; z++)
    #pragma unroll
    for (int mi = 0; mi < 4; mi++) { acc[z][mi][0] = z4; acc[z][mi][1] = z4; }

  // ---- prologue: stage tile 0 into buf 0
  #pragma unroll
  for (int u = 0; u < 4; u++) {
    int ca = u * 4 + w;   // 0..15
    async16(&xb16[(size_t)(m0 + ca * 8 + row8) * EMB + 0 + csw], &As[ca * 512]);
  }
  #pragma unroll
  for (int u = 0; u < 6; u++) {
    int cb = u * 4 + w, z = cb >> 3, r8 = cb & 7;
    const u16* Wt = (z == 0) ? WqT : (z == 1) ? WkT : WvT;
    async16(&Wt[(size_t)(n0 + r8 * 8 + row8) * EMB + 0 + csw],
            &Bs[z * 4096 + r8 * 512]);
  }
  __syncthreads();

  for (int tt = 0; tt < 8; tt++) {
    const int cur = tt & 1;
    if (tt < 7) {
      const int k1 = (tt + 1) * 64;
      const int nb = (cur ^ 1);
      #pragma unroll
      for (int u = 0; u < 4; u++) {
        int ca = u * 4 + w;
        async16(&xb16[(size_t)(m0 + ca * 8 + row8) * EMB + k1 + csw],
                &As[nb * 8192 + ca * 512]);
      }
      #pragma unroll
      for (int u = 0; u < 6; u++) {
        int cb = u * 4 + w, z = cb >> 3, r8 = cb & 7;
        const u16* Wt = (z == 0) ? WqT : (z == 1) ? WkT : WvT;
        async16(&Wt[(size_t)(n0 + r8 * 8 + row8) * EMB + k1 + csw],
                &Bs[nb * 12288 + z * 4096 + r8 * 512]);
      }
    }
    #pragma unroll
    for (int kk = 0; kk < 64; kk += 32) {
      const int u0 = ((((kk >> 3) + q) ^ (c & 7))) * 8;   // de-swizzle unit
      bf16x8 af[4];
      #pragma unroll
      for (int mi = 0; mi < 4; mi++)
        af[mi] = *reinterpret_cast<const bf16x8*>(
            &As[cur * 8192 + (wm + mi * 16 + c) * 64 + u0]);
      #pragma unroll
      for (int z = 0; z < 3; z++) {
        bf16x8 b0v = *reinterpret_cast<const bf16x8*>(
            &Bs[cur * 12288 + z * 4096 + (wn + c) * 64 + u0]);
        bf16x8 b1v = *reinterpret_cast<const bf16x8*>(
            &Bs[cur * 12288 + z * 4096 + (wn + 16 + c) * 64 + u0]);
        #pragma unroll
        for (int mi = 0; mi < 4; mi++) {
          acc[z][mi][0] = MFMA16(af[mi], b0v, acc[z][mi][0]);
          acc[z][mi][1] = MFMA16(af[mi], b1v, acc[z][mi][1]);
        }
      }
    }
    __syncthreads();
  }

  float bb[3][2];
  #pragma unroll
  for (int z = 0; z < 3; z++) {
    const void* bias = (z == 0) ? bq : (z == 1) ? bk : bv;
    bb[z][0] = load1_any(bias, n0 + wn + c, isf32);
    bb[z][1] = load1_any(bias, n0 + wn + 16 + c, isf32);
  }
  const int b = m0 >> 13, s0t = m0 & (SEQL - 1);

  // Q, K: [bh][s][d], scaled
  #pragma unroll
  for (int z = 0; z < 2; z++) {
    u16* dst = z ? Kb : Qb;
    #pragma unroll
    for (int mi = 0; mi < 4; mi++)
      #pragma unroll
      for (int i = 0; i < 4; i++) {
        int s = s0t + wm + mi * 16 + q * 4 + i;
        size_t rowb = ((size_t)((b * NH + h) * SEQL + s)) * HD;
        dst[rowb + wn + c]      = f2bf((acc[z][mi][0][i] + bb[z][0]) * QSCALE);
        dst[rowb + wn + 16 + c] = f2bf((acc[z][mi][1][i] + bb[z][1]) * QSCALE);
      }
  }

  // V: transpose through LDS -> VbT [bh][d][s] (reuses smem head: 8695 < 16384)
  __syncthreads();
  #pragma unroll
  for (int mi = 0; mi < 4; mi++)
    #pragma unroll
    for (int i = 0; i < 4; i++) {
      int ml = wm + mi * 16 + q * 4 + i;
      smem[(wn + c) * 136 + ml]      = f2bf(acc[2][mi][0][i] + bb[2][0]);
      smem[(wn + 16 + c) * 136 + ml] = f2bf(acc[2][mi][1][i] + bb[2][1]);
    }
  __syncthreads();
  const int nl = t >> 2, cq2 = (t & 3) * 32;
  #pragma unroll
  for (int u = 0; u < 4; u++)
    *reinterpret_cast<int4*>(&VbT[((size_t)((b * NH + h) * HD + nl)) * SEQL + s0t + cq2 + 8 * u]) =
        *reinterpret_cast<int4*>(&smem[nl * 136 + cq2 + 8 * u]);
}

// ------------------------------------------------------------- kernel_2 softmax + colsums (fp32)
__global__ __launch_bounds__(256) void k2_softmax_kernel(
    const float* __restrict__ qL, const float* __restrict__ kL,
    float* __restrict__ K2, float* __restrict__ cs)
{
  __shared__ float qs[64 * 65], ks[64 * 65], ps[64 * 65];
  const int t = threadIdx.x, bh = blockIdx.x;
  const int r = t >> 2, cb = (t & 3) << 4;
  #pragma unroll
  for (int i = 0; i < 16; i++) {
    qs[r * 65 + cb + i] = qL[((size_t)bh * LM + r) * HD + cb + i];
    ks[r * 65 + cb + i] = kL[((size_t)bh * LM + r) * HD + cb + i];
  }
  __syncthreads();
  float lg[16] = {};
  for (int d = 0; d < HD; d++) {
    float a = qs[r * 65 + d];
    #pragma unroll
    for (int i = 0; i < 16; i++) lg[i] = fmaf(a, ks[(cb + i) * 65 + d], lg[i]);
  }
  float m = lg[0];
  #pragma unroll
  for (int i = 1; i < 16; i++) m = fmaxf(m, lg[i]);
  m = fmaxf(m, __shfl_xor(m, 1));
  m = fmaxf(m, __shfl_xor(m, 2));
  float s = 0.f;
  #pragma unroll
  for (int i = 0; i < 16; i++) { lg[i] = __expf(lg[i] - m); s += lg[i]; }
  s += __shfl_xor(s, 1);
  s += __shfl_xor(s, 2);
  const float inv = 1.0f / s;
  #pragma unroll
  for (int i = 0; i < 16; i++) {
    float p = lg[i] * inv;
    ps[r * 65 + cb + i] = p;
    K2[((size_t)bh * LM + r) * LM + cb + i] = p;
  }
  __syncthreads();
  if (t < 64) {
    float c = 0.f;
    for (int rr = 0; rr < 64; rr++) c += ps[rr * 65 + t];
    cs[bh * LM + t] = c;
  }
}

// ------------------------------------------------------------- Newton-Schulz inverse, split-bf16 MFMA
__device__ __forceinline__ void mm_split(const u16* Ah, const u16* Al,
                                         const u16* Bh, const u16* Bl,
                                         int w, int lane, f32x4* out)
{
  const int q = lane >> 4, c = lane & 15;
  bf16x8 ah[2], al[2];
  #pragma unroll
  for (int k2 = 0; k2 < 2; k2++) {
    ah[k2] = *reinterpret_cast<const bf16x8*>(&Ah[(w * 16 + c) * 72 + k2 * 32 + q * 8]);
    al[k2] = *reinterpret_cast<const bf16x8*>(&Al[(w * 16 + c) * 72 + k2 * 32 + q * 8]);
  }
  #pragma unroll
  for (int nb = 0; nb < 4; nb++) {
    f32x4 acc = {0.f, 0.f, 0.f, 0.f};
    #pragma unroll
    for (int k2 = 0; k2 < 2; k2++) {
      bf16x8 bh_ = *reinterpret_cast<const bf16x8*>(&Bh[(nb * 16 + c) * 72 + k2 * 32 + q * 8]);
      bf16x8 bl_ = *reinterpret_cast<const bf16x8*>(&Bl[(nb * 16 + c) * 72 + k2 * 32 + q * 8]);
      acc = MFMA16(ah[k2], bh_, acc);
      acc = MFMA16(ah[k2], bl_, acc);
      acc = MFMA16(al[k2], bh_, acc);
    }
    out[nb] = acc;
  }
}

__global__ __launch_bounds__(256) void ns_inverse_kernel(
    const float* __restrict__ K2, const float* __restrict__ cs,
    float* __restrict__ Vi)
{
  __shared__ u16 K2h[64 * 72], K2l[64 * 72];   // K2, A-form [m][k]
  __shared__ u16 VAh[64 * 72], VAl[64 * 72];   // V,  A-form [m][k]
  __shared__ u16 VTh[64 * 72], VTl[64 * 72];   // V^T, B-form [n][k]
  __shared__ u16 KVh[64 * 72], KVl[64 * 72];   // KV, A-form
  __shared__ u16 Th [64 * 72], Tl [64 * 72];   // (cI - X)^T, B-form
  __shared__ float red[256];
  const int t = threadIdx.x, bh = blockIdx.x;
  const int w = t >> 6, lane = t & 63, q = lane >> 4, c = lane & 15;

  float m = -1e30f;
  for (int i = t; i < BH * LM; i += 256) m = fmaxf(m, cs[i]);
  red[t] = m;
  __syncthreads();
  for (int off = 128; off; off >>= 1) {
    if (t < off) red[t] = fmaxf(red[t], red[t + off]);
    __syncthreads();
  }
  const float ginv = 1.0f / red[0];
  __syncthreads();

  {
    const int r = t >> 2, cb = (t & 3) << 4;
    #pragma unroll
    for (int i = 0; i < 16; i++) {
      float v = K2[((size_t)bh * LM + r) * LM + cb + i];
      u16 h1 = f2bf(v);
      K2h[r * 72 + cb + i] = h1;
      K2l[r * 72 + cb + i] = f2bf(v - bf2f(h1));
      float sv = v * ginv;
      u16 h2 = f2bf(sv);
      u16 l2 = f2bf(sv - bf2f(h2));
      VTh[r * 72 + cb + i] = h2;
      VTl[r * 72 + cb + i] = l2;
      VAh[(cb + i) * 72 + r] = h2;
      VAl[(cb + i) * 72 + r] = l2;
    }
  }
  __syncthreads();

  f32x4 o[4];
  for (int it = 0; it < 6; it++) {
    mm_split(K2h, K2l, VTh, VTl, w, lane, o);
    __syncthreads();
    #pragma unroll
    for (int nb = 0; nb < 4; nb++)
      #pragma unroll
      for (int i = 0; i < 4; i++) {
        const int row = w * 16 + q * 4 + i, col = nb * 16 + c;
        const float v = o[nb][i];
        const u16 h1 = f2bf(v);
        KVh[row * 72 + col] = h1;
        KVl[row * 72 + col] = f2bf(v - bf2f(h1));
        const float tv = (row == col ? 7.0f : 0.0f) - v;
        const u16 h2 = f2bf(tv);
        Th[col * 72 + row] = h2;
        Tl[col * 72 + row] = f2bf(tv - bf2f(h2));
      }
    __syncthreads();
    mm_split(KVh, KVl, Th, Tl, w, lane, o);
    __syncthreads();
    #pragma unroll
    for (int nb = 0; nb < 4; nb++)
      #pragma unroll
      for (int i = 0; i < 4; i++) {
        const int row = w * 16 + q * 4 + i, col = nb * 16 + c;
        const float tv = (row == col ? 15.0f : 0.0f) - o[nb][i];
        const u16 h2 = f2bf(tv);
        Th[col * 72 + row] = h2;
        Tl[col * 72 + row] = f2bf(tv - bf2f(h2));
      }
    __syncthreads();
    mm_split(KVh, KVl, Th, Tl, w, lane, o);
    __syncthreads();
    #pragma unroll
    for (int nb = 0; nb < 4; nb++)
      #pragma unroll
      for (int i = 0; i < 4; i++) {
        const int row = w * 16 + q * 4 + i, col = nb * 16 + c;
        const float tv = (row == col ? 13.0f : 0.0f) - o[nb][i];
        const u16 h2 = f2bf(tv);
        Th[col * 72 + row] = h2;
        Tl[col * 72 + row] = f2bf(tv - bf2f(h2));
      }
    __syncthreads();
    mm_split(VAh, VAl, Th, Tl, w, lane, o);
    __syncthreads();
    #pragma unroll
    for (int nb = 0; nb < 4; nb++)
      #pragma unroll
      for (int i = 0; i < 4; i++) {
        const int row = w * 16 + q * 4 + i, col = nb * 16 + c;
        const float v = 0.25f * o[nb][i];
        const u16 h1 = f2bf(v);
        const u16 l1 = f2bf(v - bf2f(h1));
        VAh[row * 72 + col] = h1;
        VAl[row * 72 + col] = l1;
        VTh[col * 72 + row] = h1;
        VTl[col * 72 + row] = l1;
        if (it == 5) Vi[((size_t)bh * LM + row) * LM + col] = v;
      }
    __syncthreads();
  }
}

// ------------------------------------------------------------- MFMA kernel_3 @ v (split-K partials) v2
__global__ __launch_bounds__(256) void k3v_kernel(
    const u16* __restrict__ qLb, const u16* __restrict__ Kb, const u16* __restrict__ VbT,
    float* __restrict__ pnum, float* __restrict__ pden)
{
  __shared__ u16 Ks[64 * 72], Vs[2][64 * 72], Ps[64 * 72];
  __shared__ float denL[256];
  const int t = threadIdx.x, ch = blockIdx.x, bh = blockIdx.y;
  const int w = t >> 6, lane = t & 63, q = lane >> 4, c = lane & 15;
  const int sr = t >> 2, sp = (t & 3) * 16;

  bf16x8 aq[4][2];
  #pragma unroll
  for (int mi = 0; mi < 4; mi++)
    #pragma unroll
    for (int k2 = 0; k2 < 2; k2++)
      aq[mi][k2] = *reinterpret_cast<const bf16x8*>(
          &qLb[((size_t)bh * LM + mi * 16 + c) * HD + k2 * 32 + q * 8]);

  f32x4 z4 = {0.f, 0.f, 0.f, 0.f};
  f32x4 nacc[4];
  #pragma unroll
  for (int mi = 0; mi < 4; mi++) nacc[mi] = z4;
  float denr[16] = {};

  // prologue loads (sub 0)
  int4 kr0, kr1, vr0, vr1;
  {
    const int s0 = ch * CHS;
    const u16* kp = &Kb[((size_t)bh * SEQL + s0 + sr) * HD + sp];
    const u16* vp = &VbT[((size_t)(bh * HD + sr)) * SEQL + s0 + sp];
    kr0 = *reinterpret_cast<const int4*>(kp);
    kr1 = *reinterpret_cast<const int4*>(kp + 8);
    vr0 = *reinterpret_cast<const int4*>(vp);
    vr1 = *reinterpret_cast<const int4*>(vp + 8);
  }

  for (int sub = 0; sub < 8; sub++) {
    const int cur = sub & 1;
    *reinterpret_cast<int4*>(&Ks[sr * 72 + sp])     = kr0;
    *reinterpret_cast<int4*>(&Ks[sr * 72 + sp + 8]) = kr1;
    *reinterpret_cast<int4*>(&Vs[cur][sr * 72 + sp])     = vr0;
    *reinterpret_cast<int4*>(&Vs[cur][sr * 72 + sp + 8]) = vr1;
    __syncthreads();
    f32x4 sacc[4];
    #pragma unroll
    for (int mi = 0; mi < 4; mi++) sacc[mi] = z4;
    bf16x8 bk0 = *reinterpret_cast<const bf16x8*>(&Ks[(w * 16 + c) * 72 + q * 8]);
    bf16x8 bk1 = *reinterpret_cast<const bf16x8*>(&Ks[(w * 16 + c) * 72 + 32 + q * 8]);
    #pragma unroll
    for (int mi = 0; mi < 4; mi++) {
      sacc[mi] = MFMA16(aq[mi][0], bk0, sacc[mi]);
      sacc[mi] = MFMA16(aq[mi][1], bk1, sacc[mi]);
    }
    #pragma unroll
    for (int mi = 0; mi < 4; mi++)
      #pragma unroll
      for (int i = 0; i < 4; i++) {
        float p = __expf(sacc[mi][i]);
        denr[mi * 4 + i] += p;
        Ps[(mi * 16 + q * 4 + i) * 72 + w * 16 + c] = f2bf(p);
      }
    __syncthreads();
    if (sub < 7) {
      const int s1 = ch * CHS + (sub + 1) * 64;
      const u16* kp = &Kb[((size_t)bh * SEQL + s1 + sr) * HD + sp];
      const u16* vp = &VbT[((size_t)(bh * HD + sr)) * SEQL + s1 + sp];
      kr0 = *reinterpret_cast<const int4*>(kp);
      kr1 = *reinterpret_cast<const int4*>(kp + 8);
      vr0 = *reinterpret_cast<const int4*>(vp);
      vr1 = *reinterpret_cast<const int4*>(vp + 8);
    }
    #pragma unroll
    for (int k2 = 0; k2 < 2; k2++) {
      bf16x8 bv_ = *reinterpret_cast<const bf16x8*>(&Vs[cur][(w * 16 + c) * 72 + k2 * 32 + q * 8]);
      #pragma unroll
      for (int mi = 0; mi < 4; mi++) {
        bf16x8 ap = *reinterpret_cast<const bf16x8*>(&Ps[(mi * 16 + c) * 72 + k2 * 32 + q * 8]);
        nacc[mi] = MFMA16(ap, bv_, nacc[mi]);
      }
    }
  }
  #pragma unroll
  for (int mi = 0; mi < 4; mi++)
    #pragma unroll
    for (int i = 0; i < 4; i++)
      pnum[(((size_t)bh * NCH + ch) * LM + mi * 16 + q * 4 + i) * HD + w * 16 + c] = nacc[mi][i];
  #pragma unroll
  for (int v = 0; v < 16; v++) {
    denr[v] += __shfl_xor(denr[v], 1);
    denr[v] += __shfl_xor(denr[v], 2);
    denr[v] += __shfl_xor(denr[v], 4);
    denr[v] += __shfl_xor(denr[v], 8);
  }
  if (c == 0) {
    #pragma unroll
    for (int mi = 0; mi < 4; mi++)
      #pragma unroll
      for (int i = 0; i < 4; i++)
        denL[w * 64 + mi * 16 + q * 4 + i] = denr[mi * 4 + i];
  }
  __syncthreads();
  if (t < 64)
    pden[((size_t)bh * NCH + ch) * LM + t] = denL[t] + denL[64 + t] + denL[128 + t] + denL[192 + t];
}

// ------------------------------------------------------------- reduce partials; W2T = (Vi @ normalize(k3 v))^T bf16
__global__ __launch_bounds__(256) void k3v_w2_kernel(
    const float* __restrict__ pnum, const float* __restrict__ pden,
    const float* __restrict__ Vi, u16* __restrict__ W2T)
{
  __shared__ float Vs[64 * 65], Ms[64 * 65], den[64];
  const int t = threadIdx.x, bh = blockIdx.x;
  const int r = t >> 2, cb = (t & 3) << 4;
  #pragma unroll
  for (int i = 0; i < 16; i++) Vs[r * 65 + cb + i] = Vi[((size_t)bh * LM + r) * LM + cb + i];
  float acc[16] = {};
  for (int ch = 0; ch < NCH; ch++) {
    const float* p = pnum + (((size_t)bh * NCH + ch) * LM + r) * HD + cb;
    #pragma unroll
    for (int i = 0; i < 16; i++) acc[i] += p[i];
  }
  if ((t & 3) == 0) {
    float d = 0.f;
    for (int ch = 0; ch < NCH; ch++) d += pden[((size_t)bh * NCH + ch) * LM + r];
    den[r] = d;
  }
  __syncthreads();
  const float dinv = 1.0f / den[r];
  #pragma unroll
  for (int i = 0; i < 16; i++) Ms[r * 65 + cb + i] = acc[i] * dinv;
  __syncthreads();
  float o[16] = {};
  for (int k = 0; k < 64; k++) {
    float a = Vs[r * 65 + k];
    #pragma unroll
    for (int i = 0; i < 16; i++) o[i] = fmaf(a, Ms[k * 65 + cb + i], o[i]);
  }
  #pragma unroll
  for (int i = 0; i < 16; i++)
    W2T[((size_t)bh * HD + cb + i) * LM + r] = f2bf(o[i]);
}

// ------------------------------------------------------------- MFMA kernel_1 softmax @ W2
__global__ __launch_bounds__(256) void final_kernel(
    const u16* __restrict__ Qb, const u16* __restrict__ kLb, const u16* __restrict__ W2T,
    u16* __restrict__ pre)
{
  __shared__ u16 Ps[64 * 72];
  __shared__ float mxL[256], smL[256];
  const int t = threadIdx.x, st = blockIdx.x, bh = blockIdx.y;
  const int w = t >> 6, lane = t & 63, q = lane >> 4, c = lane & 15;
  const int sb = st * 64;

  bf16x8 aq[4][2], bkL[2], bw2[2];
  #pragma unroll
  for (int mi = 0; mi < 4; mi++)
    #pragma unroll
    for (int k2 = 0; k2 < 2; k2++)
      aq[mi][k2] = *reinterpret_cast<const bf16x8*>(
          &Qb[((size_t)bh * SEQL + sb + mi * 16 + c) * HD + k2 * 32 + q * 8]);
  #pragma unroll
  for (int k2 = 0; k2 < 2; k2++) {
    bkL[k2] = *reinterpret_cast<const bf16x8*>(
        &kLb[((size_t)bh * LM + w * 16 + c) * HD + k2 * 32 + q * 8]);
    bw2[k2] = *reinterpret_cast<const bf16x8*>(
        &W2T[((size_t)bh * HD + w * 16 + c) * LM + k2 * 32 + q * 8]);
  }

  f32x4 z4 = {0.f, 0.f, 0.f, 0.f};
  f32x4 sacc[4];
  #pragma unroll
  for (int mi = 0; mi < 4; mi++) sacc[mi] = z4;
  #pragma unroll
  for (int k2 = 0; k2 < 2; k2++)
    #pragma unroll
    for (int mi = 0; mi < 4; mi++)
      sacc[mi] = MFMA16(aq[mi][k2], bkL[k2], sacc[mi]);

  float mx[16];
  #pragma unroll
  for (int v = 0; v < 16; v++) {
    mx[v] = sacc[v >> 2][v & 3];
    mx[v] = fmaxf(mx[v], __shfl_xor(mx[v], 1));
    mx[v] = fmaxf(mx[v], __shfl_xor(mx[v], 2));
    mx[v] = fmaxf(mx[v], __shfl_xor(mx[v], 4));
    mx[v] = fmaxf(mx[v], __shfl_xor(mx[v], 8));
  }
  if (c == 0) {
    #pragma unroll
    for (int mi = 0; mi < 4; mi++)
      #pragma unroll
      for (int i = 0; i < 4; i++)
        mxL[w * 64 + mi * 16 + q * 4 + i] = mx[mi * 4 + i];
  }
  __syncthreads();
  float p[16], dn[16];
  #pragma unroll
  for (int mi = 0; mi < 4; mi++)
    #pragma unroll
    for (int i = 0; i < 4; i++) {
      int row = mi * 16 + q * 4 + i;
      float M = fmaxf(fmaxf(mxL[row], mxL[64 + row]), fmaxf(mxL[128 + row], mxL[192 + row]));
      float pp = __expf(sacc[mi][i] - M);
      p[mi * 4 + i] = pp;
      dn[mi * 4 + i] = pp;
    }
  #pragma unroll
  for (int v = 0; v < 16; v++) {
    dn[v] += __shfl_xor(dn[v], 1);
    dn[v] += __shfl_xor(dn[v], 2);
    dn[v] += __shfl_xor(dn[v], 4);
    dn[v] += __shfl_xor(dn[v], 8);
  }
  if (c == 0) {
    #pragma unroll
    for (int mi = 0; mi < 4; mi++)
      #pragma unroll
      for (int i = 0; i < 4; i++)
        smL[w * 64 + mi * 16 + q * 4 + i] = dn[mi * 4 + i];
  }
  #pragma unroll
  for (int mi = 0; mi < 4; mi++)
    #pragma unroll
    for (int i = 0; i < 4; i++)
      Ps[(mi * 16 + q * 4 + i) * 72 + w * 16 + c] = f2bf(p[mi * 4 + i]);
  __syncthreads();

  f32x4 oacc[4];
  #pragma unroll
  for (int mi = 0; mi < 4; mi++) oacc[mi] = z4;
  #pragma unroll
  for (int k2 = 0; k2 < 2; k2++)
    #pragma unroll
    for (int mi = 0; mi < 4; mi++) {
      bf16x8 ap = *reinterpret_cast<const bf16x8*>(&Ps[(mi * 16 + c) * 72 + k2 * 32 + q * 8]);
      oacc[mi] = MFMA16(ap, bw2[k2], oacc[mi]);
    }
  #pragma unroll
  for (int mi = 0; mi < 4; mi++)
    #pragma unroll
    for (int i = 0; i < 4; i++) {
      int row = mi * 16 + q * 4 + i;
      float den = smL[row] + smL[64 + row] + smL[128 + row] + smL[192 + row];
      float v = oacc[mi][i] / den;
      pre[((size_t)((bh >> 3) * SEQL + sb + row)) * EMB + (bh & 7) * HD + w * 16 + c] = f2bf(v);
    }
}

// ------------------------------------------------------------- MFMA out = pre @ Wo + bo v2
__global__ __launch_bounds__(256, 2) void out_proj_kernel(
    const u16* __restrict__ pre, const u16* __restrict__ WoT, const void* bo,
    const int* flag, void* out)
{
  __shared__ u16 As[2 * 128 * 64];   // linear rows, unit-swizzled cols
  __shared__ u16 Bs[2 * 128 * 64];
  const int t = threadIdx.x;
  const int m0 = blockIdx.x * 128, n0 = blockIdx.y * 128;
  const int isf32 = flag[0];
  const int w = t >> 6, lane = t & 63, q = lane >> 4, c = lane & 15;
  const int wm = (w >> 1) * 64, wn = (w & 1) * 64;
  const int row8 = lane >> 3;
  const int colsw = ((lane & 7) ^ row8) * 8;

  f32x4 acc[4][4];
  f32x4 z4 = {0.f, 0.f, 0.f, 0.f};
  #pragma unroll
  for (int mi = 0; mi < 4; mi++)
    #pragma unroll
    for (int ni = 0; ni < 4; ni++) acc[mi][ni] = z4;

  // prologue: tile 0
  #pragma unroll
  for (int u = 0; u < 4; u++) {
    int chA = u * 4 + w;
    async16(&pre[(size_t)(m0 + chA * 8 + row8) * EMB + 0 + colsw], &As[chA * 512]);
    async16(&WoT[(size_t)(n0 + chA * 8 + row8) * EMB + 0 + colsw], &Bs[chA * 512]);
  }
  __syncthreads();

  for (int tt = 0; tt < 8; tt++) {
    const int cur = tt & 1;
    if (tt < 7) {
      const int k1 = (tt + 1) * 64;
      #pragma unroll
      for (int u = 0; u < 4; u++) {
        int chA = u * 4 + w;
        async16(&pre[(size_t)(m0 + chA * 8 + row8) * EMB + k1 + colsw],
                &As[(cur ^ 1) * 8192 + chA * 512]);
        async16(&WoT[(size_t)(n0 + chA * 8 + row8) * EMB + k1 + colsw],
                &Bs[(cur ^ 1) * 8192 + chA * 512]);
      }
    }
    #pragma unroll
    for (int kk = 0; kk < 64; kk += 32) {
      const int u0 = ((((kk >> 3) + q) ^ (c & 7))) * 8;
      bf16x8 af[4], bfv[4];
      #pragma unroll
      for (int mi = 0; mi < 4; mi++)
        af[mi] = *reinterpret_cast<const bf16x8*>(&As[cur * 8192 + (wm + mi * 16 + c) * 64 + u0]);
      #pragma unroll
      for (int ni = 0; ni < 4; ni++)
        bfv[ni] = *reinterpret_cast<const bf16x8*>(&Bs[cur * 8192 + (wn + ni * 16 + c) * 64 + u0]);
      #pragma unroll
      for (int mi = 0; mi < 4; mi++)
        #pragma unroll
        for (int ni = 0; ni < 4; ni++)
          acc[mi][ni] = MFMA16(af[mi], bfv[ni], acc[mi][ni]);
    }
    __syncthreads();
  }
  float bb[4];
  #pragma unroll
  for (int ni = 0; ni < 4; ni++) bb[ni] = load1_any(bo, n0 + wn + ni * 16 + c, isf32);
  #pragma unroll
  for (int mi = 0; mi < 4; mi++)
    #pragma unroll
    for (int i = 0; i < 4; i++) {
      int m = m0 + wm + mi * 16 + q * 4 + i;
      #pragma unroll
      for (int ni = 0; ni < 4; ni++) {
        int n = n0 + wn + ni * 16 + c;
        float v = acc[mi][ni][i] + bb[ni];
        if (isf32) ((float*)out)[(size_t)m * EMB + n] = v;
        else       ((u16*)out)[(size_t)m * EMB + n] = f2bf(v);
      }
    }
}

// ------------------------------------------------------------- launch
extern "C" void kernel_launch(void* const* d_in, const int* in_sizes, int n_in,
                              void* d_out, int out_size, void* d_ws, size_t ws_size,
                              hipStream_t stream)
{
  (void)in_sizes; (void)n_in; (void)out_size; (void)ws_size;
  const void* x  = d_in[0];
  const void* Wq = d_in[1];
  const void* bq = d_in[2];
  const void* Wk = d_in[3];
  const void* bk = d_in[4];
  const void* Wv = d_in[5];
  const void* bv = d_in[6];
  const void* Wo = d_in[7];
  const void* bo = d_in[8];

  float* ws = (float*)d_ws;
  int*   flag  = (int*)ws;                         // 64 floats
  float* xmean = ws + 64;                          // 131072
  float* qL    = xmean + 131072;                   // 131072
  float* kL    = qL + 131072;                      // 131072
  float* K2    = kL + 131072;                      // 131072
  float* cs    = K2 + 131072;                      // 2048
  float* Vi    = cs + 2048;                        // 131072
  float* pnum  = Vi + 131072;                      // 2097152
  float* pden  = pnum + 2097152;                   // 32768
  u16* WqT = (u16*)(pden + 32768);                 // 262144 u16 each
  u16* WkT = WqT + 262144;
  u16* WvT = WkT + 262144;
  u16* WoT = WvT + 262144;
  u16* qLb = WoT + 262144;                         // 131072
  u16* kLb = qLb + 131072;                         // 131072
  u16* W2T = kLb + 131072;                         // 131072
  u16* Qb  = W2T + 131072;                         // 16777216
  u16* Kb  = Qb + 16777216;                        // 16777216
  u16* VbT = Kb + 16777216;                        // 16777216
  u16* xb16 = VbT + 16777216;                      // 16777216 (x as bf16, 32MB)
  u16* pre = Kb;  // alias: Kb dead after k3v_kernel; final runs after k3v_w2

  probe_kernel<<<1, 256, 0, stream>>>(x, flag);
  prep_wt_kernel<<<256, 256, 0, stream>>>(Wq, Wk, Wv, Wo, flag, WqT, WkT, WvT, WoT);
  xmean_kernel<<<BS * LM, 256, 0, stream>>>(x, flag, xmean, xb16);
  lm_proj_kernel<<<dim3(4, 8, 2), 256, 0, stream>>>(xmean, Wq, bq, Wk, bk, flag, qL, kL, qLb, kLb);
  proj_qkv_fused_kernel<<<dim3(2048), 256, 0, stream>>>(
      xb16, WqT, WkT, WvT, bq, bk, bv, flag, Qb, Kb, VbT);
  k2_softmax_kernel<<<BH, 256, 0, stream>>>(qL, kL, K2, cs);
  ns_inverse_kernel<<<BH, 256, 0, stream>>>(K2, cs, Vi);
  k3v_kernel<<<dim3(NCH, BH), 256, 0, stream>>>(qLb, Kb, VbT, pnum, pden);
  k3v_w2_kernel<<<BH, 256, 0, stream>>>(pnum, pden, Vi, W2T);
  final_kernel<<<dim3(SEQL / 64, BH), 256, 0, stream>>>(Qb, kLb, W2T, pre);
  out_proj_kernel<<<dim3(256, 4), 256, 0, stream>>>(pre, WoT, bo, flag, d_out);
}

// Round 6
// 378.603 us; speedup vs baseline: 1.3970x; 1.1454x over previous
//
#include <hip/hip_runtime.h>

#define BS 4
#define SEQL 8192
#define EMB 512
#define NH 8
#define HD 64
#define LM 64
#define SEG 128
#define BH (BS*NH)           // 32
#define NCH 16
#define CHS (SEQL/NCH)       // 512
#define QSCALE 0.35355339059327373f  // 64^(-1/4)

typedef unsigned short u16;
typedef __bf16 bf16_t;
typedef __attribute__((ext_vector_type(8))) __bf16 bf16x8;
typedef __attribute__((ext_vector_type(4))) float f32x4;

#define MFMA16(a, b, c) __builtin_amdgcn_mfma_f32_16x16x32_bf16((a), (b), (c), 0, 0, 0)

__device__ __forceinline__ float bf2f(u16 u) {
  return __uint_as_float(((unsigned int)u) << 16);
}
__device__ __forceinline__ u16 f2bf(float f) {
  unsigned int u = __float_as_uint(f);
  u += 0x7fffu + ((u >> 16) & 1u);   // RNE
  return (u16)(u >> 16);
}
__device__ __forceinline__ float load1_any(const void* p, size_t idx, int isf32) {
  return isf32 ? ((const float*)p)[idx] : bf2f(((const u16*)p)[idx]);
}
__device__ __forceinline__ void load4_any(const void* p, size_t idx, int isf32, float* dst) {
  if (isf32) {
    float4 v = *reinterpret_cast<const float4*>((const float*)p + idx);
    dst[0] = v.x; dst[1] = v.y; dst[2] = v.z; dst[3] = v.w;
  } else {
    ushort4 v = *reinterpret_cast<const ushort4*>((const u16*)p + idx);
    dst[0] = bf2f(v.x); dst[1] = bf2f(v.y); dst[2] = bf2f(v.z); dst[3] = bf2f(v.w);
  }
}
// load 8 consecutive source elems as bf16 bit patterns into o[8]
__device__ __forceinline__ void ld8_bf(const void* p, size_t idx, int isf32, u16* o) {
  if (isf32) {
    const float* f = (const float*)p + idx;
    float4 a = *reinterpret_cast<const float4*>(f);
    float4 b = *reinterpret_cast<const float4*>(f + 4);
    o[0] = f2bf(a.x); o[1] = f2bf(a.y); o[2] = f2bf(a.z); o[3] = f2bf(a.w);
    o[4] = f2bf(b.x); o[5] = f2bf(b.y); o[6] = f2bf(b.z); o[7] = f2bf(b.w);
  } else {
    *reinterpret_cast<int4*>(o) = *reinterpret_cast<const int4*>((const u16*)p + idx);
  }
}

// async global->LDS direct copy, 16B per lane; lds must be the wave-uniform
// chunk base (HW adds lane*16), gsrc is per-lane.
__device__ __forceinline__ void async16(const void* g, void* l) {
  __builtin_amdgcn_global_load_lds(
      (const __attribute__((address_space(1))) void*)g,
      (__attribute__((address_space(3))) void*)l, 16, 0, 0);
}

// ------------------------------------------------------------- dtype probe
__global__ __launch_bounds__(256) void probe_kernel(const void* x, int* flag) {
  __shared__ int cnt;
  if (threadIdx.x == 0) cnt = 0;
  __syncthreads();
  const u16* p = (const u16*)x;
  int c = 0;
  for (int j = 0; j < 16; j++) {
    u16 u = p[(size_t)(threadIdx.x * 16 + j) * 2];
    int e = (u >> 7) & 0xFF;
    if (e >= 134) c++;
  }
  atomicAdd(&cnt, c);
  __syncthreads();
  if (threadIdx.x == 0) flag[0] = (cnt > 256) ? 1 : 0;
}

// ------------------------------------------------------------- weight transposes -> bf16 WT[n][k]
__global__ __launch_bounds__(256) void prep_wt_kernel(
    const void* Wq, const void* Wk, const void* Wv, const void* Wo, const int* flag,
    u16* __restrict__ WqT, u16* __restrict__ WkT, u16* __restrict__ WvT, u16* __restrict__ WoT)
{
  __shared__ u16 Ws[64 * 72];
  const int id = blockIdx.x;
  const int z = id >> 6, tile = id & 63;
  const int k0 = (tile >> 3) * 64, n0 = (tile & 7) * 64;
  const void* W = (z == 0) ? Wq : (z == 1) ? Wk : (z == 2) ? Wv : Wo;
  u16* WT = (z == 0) ? WqT : (z == 1) ? WkT : (z == 2) ? WvT : WoT;
  const int isf32 = flag[0];
  const int t = threadIdx.x;
  const int r = t >> 2, cq = (t & 3) * 16;
  u16 tmp[8];
  #pragma unroll
  for (int u = 0; u < 2; u++) {
    ld8_bf(W, (size_t)(k0 + r) * EMB + n0 + cq + 8 * u, isf32, tmp);
    *reinterpret_cast<int4*>(&Ws[r * 72 + cq + 8 * u]) = *reinterpret_cast<int4*>(tmp);
  }
  __syncthreads();
  const int nn = t >> 2, kq = (t & 3) * 16;
  #pragma unroll
  for (int u = 0; u < 2; u++) {
    u16 o[8];
    #pragma unroll
    for (int j = 0; j < 8; j++) o[j] = Ws[(kq + 8 * u + j) * 72 + nn];
    *reinterpret_cast<int4*>(&WT[(size_t)(n0 + nn) * EMB + k0 + kq + 8 * u]) =
        *reinterpret_cast<int4*>(o);
  }
}

// ------------------------------------------------------------- x partial col-sums + x->bf16 copy
// 2048 blocks (8/CU): block = (landmark-segment bl, 16-row chunk ch).
// float4/ushort4 coalesced; partial sums LDS-reduced across the 2 row-groups.
__global__ __launch_bounds__(256) void xpart_kernel(const void* x, const int* flag,
                                                    float* __restrict__ xpart,
                                                    u16* __restrict__ xb16) {
  __shared__ float red[512];
  const int blk = blockIdx.x;            // 0..2047
  const int bl = blk >> 3, ch = blk & 7;
  const int t = threadIdx.x;
  const int isf32 = flag[0];
  const int rg = t >> 7;                 // row group 0/1
  const int c4 = (t & 127) * 4;          // column base
  const size_t base = ((size_t)bl * SEG + ch * 16) * EMB;
  float s0 = 0.f, s1 = 0.f, s2 = 0.f, s3 = 0.f;
  for (int r = rg; r < 16; r += 2) {
    size_t idx = base + (size_t)r * EMB + c4;
    if (isf32) {
      float4 v = *reinterpret_cast<const float4*>((const float*)x + idx);
      ushort4 ob;
      ob.x = f2bf(v.x); ob.y = f2bf(v.y); ob.z = f2bf(v.z); ob.w = f2bf(v.w);
      *reinterpret_cast<ushort4*>(&xb16[idx]) = ob;
      s0 += v.x; s1 += v.y; s2 += v.z; s3 += v.w;
    } else {
      ushort4 v = *reinterpret_cast<const ushort4*>((const u16*)x + idx);
      s0 += bf2f(v.x); s1 += bf2f(v.y); s2 += bf2f(v.z); s3 += bf2f(v.w);
    }
  }
  if (rg == 0) {
    red[c4] = s0; red[c4 + 1] = s1; red[c4 + 2] = s2; red[c4 + 3] = s3;
  }
  __syncthreads();
  if (rg == 1) {
    red[c4] += s0; red[c4 + 1] += s1; red[c4 + 2] += s2; red[c4 + 3] += s3;
  }
  __syncthreads();
  if (t < 128) {
    float4 o;
    o.x = red[t * 4]; o.y = red[t * 4 + 1]; o.z = red[t * 4 + 2]; o.w = red[t * 4 + 3];
    *reinterpret_cast<float4*>(&xpart[(size_t)blk * 512 + t * 4]) = o;
  }
}

// sum the 8 chunk-partials per segment -> xmean
__global__ __launch_bounds__(256) void xmean_reduce_kernel(
    const float* __restrict__ xpart, float* __restrict__ xmean) {
  const int bl = blockIdx.x;   // 0..255
  const int t = threadIdx.x;
  const int c = t * 2;
  float s0 = 0.f, s1 = 0.f;
  #pragma unroll
  for (int ch = 0; ch < 8; ch++) {
    const float* p = &xpart[((size_t)(bl * 8 + ch)) * 512 + c];
    s0 += p[0]; s1 += p[1];
  }
  xmean[(size_t)bl * EMB + c]     = s0 * (1.0f / SEG);
  xmean[(size_t)bl * EMB + c + 1] = s1 * (1.0f / SEG);
}

// ------------------------------------------------------------- landmark projections (fp32 + bf16 copies)
__global__ __launch_bounds__(256) void lm_proj_kernel(
    const float* __restrict__ xmean,
    const void* Wq, const void* bq, const void* Wk, const void* bk,
    const int* flag, float* __restrict__ qL, float* __restrict__ kL,
    u16* __restrict__ qLb, u16* __restrict__ kLb)
{
  __shared__ float As[64 * 17];
  __shared__ float Bs[16 * 64];
  const int t = threadIdx.x;
  const int m0 = blockIdx.x * 64, n0 = blockIdx.y * 64, z = blockIdx.z;
  const void* W    = z ? Wk : Wq;
  const void* bias = z ? bk : bq;
  float* dst       = z ? kL : qL;
  u16*   dstb      = z ? kLb : qLb;
  const int isf32 = flag[0];
  const int tx = t & 15, ty = t >> 4;
  const int arow = t >> 2, akk = (t & 3) << 2;
  const int brow = t >> 4, bcol = (t & 15) << 2;
  float acc[4][4] = {};
  for (int k0 = 0; k0 < EMB; k0 += 16) {
    float4 av = *reinterpret_cast<const float4*>(xmean + (size_t)(m0 + arow) * EMB + k0 + akk);
    As[arow * 17 + akk + 0] = av.x;
    As[arow * 17 + akk + 1] = av.y;
    As[arow * 17 + akk + 2] = av.z;
    As[arow * 17 + akk + 3] = av.w;
    load4_any(W, (size_t)(k0 + brow) * EMB + n0 + bcol, isf32, &Bs[brow * 64 + bcol]);
    __syncthreads();
    #pragma unroll
    for (int kk = 0; kk < 16; kk++) {
      float a[4], b[4];
      #pragma unroll
      for (int i = 0; i < 4; i++) a[i] = As[(ty * 4 + i) * 17 + kk];
      #pragma unroll
      for (int j = 0; j < 4; j++) b[j] = Bs[kk * 64 + tx * 4 + j];
      #pragma unroll
      for (int i = 0; i < 4; i++)
        #pragma unroll
        for (int j = 0; j < 4; j++)
          acc[i][j] = fmaf(a[i], b[j], acc[i][j]);
    }
    __syncthreads();
  }
  #pragma unroll
  for (int i = 0; i < 4; i++) {
    int m = m0 + ty * 4 + i;
    int b = m >> 6, l = m & 63;
    #pragma unroll
    for (int j = 0; j < 4; j++) {
      int n = n0 + tx * 4 + j;
      int h = n >> 6, d = n & 63;
      float c = (acc[i][j] + load1_any(bias, n, isf32)) * QSCALE;
      size_t idx = (size_t)((b * NH + h) * LM + l) * HD + d;
      dst[idx] = c;
      dstb[idx] = f2bf(c);
    }
  }
}

// ------------------------------------------------------------- fused MFMA QKV projection v5
// Both A (xb16, or x directly if already bf16) and B (WT) staged via
// global_load_lds with pre-swizzled per-lane source cols + linear LDS dest.
// Double-buffered, ONE __syncthreads per k-tile.
__global__ __launch_bounds__(256, 2) void proj_qkv_fused_kernel(
    const void* x, const u16* __restrict__ xb16, const u16* __restrict__ WqT,
    const u16* __restrict__ WkT, const u16* __restrict__ WvT,
    const void* bq, const void* bk, const void* bv, const int* flag,
    u16* __restrict__ Qb, u16* __restrict__ Kb, u16* __restrict__ VbT)
{
  __shared__ u16 smem[2 * 128 * 64 + 2 * 3 * 64 * 64];   // 32KB A + 48KB B = 80KB
  u16* As = smem;                    // [2][16 chunks][512]
  u16* Bs = smem + 2 * 128 * 64;     // [2][3][8 chunks][512]
  const int t = threadIdx.x;
  const int orig = blockIdx.x;                    // XCD = orig & 7
  const int swz  = (orig & 7) * 256 + (orig >> 3);
  const int h    = swz & 7;
  const int m0   = (swz >> 3) * 128;
  const int n0   = h * 64;
  const int isf32 = flag[0];
  const u16* xs = isf32 ? xb16 : (const u16*)x;   // bf16 source for A
  const int w = t >> 6, lane = t & 63, q = lane >> 4, c = lane & 15;
  const int wm = (w >> 1) * 64, wn = (w & 1) * 32;
  const int row8 = lane >> 3;                       // glds row within 8-row chunk
  const int csw  = ((lane & 7) ^ row8) * 8;         // pre-swizzled source col

  f32x4 acc[3][4][2];
  f32x4 z4 = {0.f, 0.f, 0.f, 0.f};
  #pragma unroll
  for (int z = 0; z < 3; z++)
    #pragma unroll
    for (int mi = 0; mi < 4; mi++) { acc[z][mi][0] = z4; acc[z][mi][1] = z4; }

  // ---- prologue: stage tile 0 into buf 0
  #pragma unroll
  for (int u = 0; u < 4; u++) {
    int ca = u * 4 + w;   // 0..15
    async16(&xs[(size_t)(m0 + ca * 8 + row8) * EMB + 0 + csw], &As[ca * 512]);
  }
  #pragma unroll
  for (int u = 0; u < 6; u++) {
    int cb = u * 4 + w, z = cb >> 3, r8 = cb & 7;
    const u16* Wt = (z == 0) ? WqT : (z == 1) ? WkT : WvT;
    async16(&Wt[(size_t)(n0 + r8 * 8 + row8) * EMB + 0 + csw],
            &Bs[z * 4096 + r8 * 512]);
  }
  __syncthreads();

  for (int tt = 0; tt < 8; tt++) {
    const int cur = tt & 1;
    if (tt < 7) {
      const int k1 = (tt + 1) * 64;
      const int nb = (cur ^ 1);
      #pragma unroll
      for (int u = 0; u < 4; u++) {
        int ca = u * 4 + w;
        async16(&xs[(size_t)(m0 + ca * 8 + row8) * EMB + k1 + csw],
                &As[nb * 8192 + ca * 512]);
      }
      #pragma unroll
      for (int u = 0; u < 6; u++) {
        int cb = u * 4 + w, z = cb >> 3, r8 = cb & 7;
        const u16* Wt = (z == 0) ? WqT : (z == 1) ? WkT : WvT;
        async16(&Wt[(size_t)(n0 + r8 * 8 + row8) * EMB + k1 + csw],
                &Bs[nb * 12288 + z * 4096 + r8 * 512]);
      }
    }
    #pragma unroll
    for (int kk = 0; kk < 64; kk += 32) {
      const int u0 = ((((kk >> 3) + q) ^ (c & 7))) * 8;   // de-swizzle unit
      bf16x8 af[4];
      #pragma unroll
      for (int mi = 0; mi < 4; mi++)
        af[mi] = *reinterpret_cast<const bf16x8*>(
            &As[cur * 8192 + (wm + mi * 16 + c) * 64 + u0]);
      #pragma unroll
      for (int z = 0; z < 3; z++) {
        bf16x8 b0v = *reinterpret_cast<const bf16x8*>(
            &Bs[cur * 12288 + z * 4096 + (wn + c) * 64 + u0]);
        bf16x8 b1v = *reinterpret_cast<const bf16x8*>(
            &Bs[cur * 12288 + z * 4096 + (wn + 16 + c) * 64 + u0]);
        #pragma unroll
        for (int mi = 0; mi < 4; mi++) {
          acc[z][mi][0] = MFMA16(af[mi], b0v, acc[z][mi][0]);
          acc[z][mi][1] = MFMA16(af[mi], b1v, acc[z][mi][1]);
        }
      }
    }
    __syncthreads();
  }

  float bb[3][2];
  #pragma unroll
  for (int z = 0; z < 3; z++) {
    const void* bias = (z == 0) ? bq : (z == 1) ? bk : bv;
    bb[z][0] = load1_any(bias, n0 + wn + c, isf32);
    bb[z][1] = load1_any(bias, n0 + wn + 16 + c, isf32);
  }
  const int b = m0 >> 13, s0t = m0 & (SEQL - 1);

  // Q, K: [bh][s][d], scaled
  #pragma unroll
  for (int z = 0; z < 2; z++) {
    u16* dst = z ? Kb : Qb;
    #pragma unroll
    for (int mi = 0; mi < 4; mi++)
      #pragma unroll
      for (int i = 0; i < 4; i++) {
        int s = s0t + wm + mi * 16 + q * 4 + i;
        size_t rowb = ((size_t)((b * NH + h) * SEQL + s)) * HD;
        dst[rowb + wn + c]      = f2bf((acc[z][mi][0][i] + bb[z][0]) * QSCALE);
        dst[rowb + wn + 16 + c] = f2bf((acc[z][mi][1][i] + bb[z][1]) * QSCALE);
      }
  }

  // V: transpose through LDS -> VbT [bh][d][s] (reuses smem head: 8695 < 16384)
  __syncthreads();
  #pragma unroll
  for (int mi = 0; mi < 4; mi++)
    #pragma unroll
    for (int i = 0; i < 4; i++) {
      int ml = wm + mi * 16 + q * 4 + i;
      smem[(wn + c) * 136 + ml]      = f2bf(acc[2][mi][0][i] + bb[2][0]);
      smem[(wn + 16 + c) * 136 + ml] = f2bf(acc[2][mi][1][i] + bb[2][1]);
    }
  __syncthreads();
  const int nl = t >> 2, cq2 = (t & 3) * 32;
  #pragma unroll
  for (int u = 0; u < 4; u++)
    *reinterpret_cast<int4*>(&VbT[((size_t)((b * NH + h) * HD + nl)) * SEQL + s0t + cq2 + 8 * u]) =
        *reinterpret_cast<int4*>(&smem[nl * 136 + cq2 + 8 * u]);
}

// ------------------------------------------------------------- kernel_2 softmax + colsums (fp32)
__global__ __launch_bounds__(256) void k2_softmax_kernel(
    const float* __restrict__ qL, const float* __restrict__ kL,
    float* __restrict__ K2, float* __restrict__ cs)
{
  __shared__ float qs[64 * 65], ks[64 * 65], ps[64 * 65];
  const int t = threadIdx.x, bh = blockIdx.x;
  const int r = t >> 2, cb = (t & 3) << 4;
  #pragma unroll
  for (int i = 0; i < 16; i++) {
    qs[r * 65 + cb + i] = qL[((size_t)bh * LM + r) * HD + cb + i];
    ks[r * 65 + cb + i] = kL[((size_t)bh * LM + r) * HD + cb + i];
  }
  __syncthreads();
  float lg[16] = {};
  for (int d = 0; d < HD; d++) {
    float a = qs[r * 65 + d];
    #pragma unroll
    for (int i = 0; i < 16; i++) lg[i] = fmaf(a, ks[(cb + i) * 65 + d], lg[i]);
  }
  float m = lg[0];
  #pragma unroll
  for (int i = 1; i < 16; i++) m = fmaxf(m, lg[i]);
  m = fmaxf(m, __shfl_xor(m, 1));
  m = fmaxf(m, __shfl_xor(m, 2));
  float s = 0.f;
  #pragma unroll
  for (int i = 0; i < 16; i++) { lg[i] = __expf(lg[i] - m); s += lg[i]; }
  s += __shfl_xor(s, 1);
  s += __shfl_xor(s, 2);
  const float inv = 1.0f / s;
  #pragma unroll
  for (int i = 0; i < 16; i++) {
    float p = lg[i] * inv;
    ps[r * 65 + cb + i] = p;
    K2[((size_t)bh * LM + r) * LM + cb + i] = p;
  }
  __syncthreads();
  if (t < 64) {
    float c = 0.f;
    for (int rr = 0; rr < 64; rr++) c += ps[rr * 65 + t];
    cs[bh * LM + t] = c;
  }
}

// ------------------------------------------------------------- Newton-Schulz inverse, split-bf16 MFMA
__device__ __forceinline__ void mm_split(const u16* Ah, const u16* Al,
                                         const u16* Bh, const u16* Bl,
                                         int w, int lane, f32x4* out)
{
  const int q = lane >> 4, c = lane & 15;
  bf16x8 ah[2], al[2];
  #pragma unroll
  for (int k2 = 0; k2 < 2; k2++) {
    ah[k2] = *reinterpret_cast<const bf16x8*>(&Ah[(w * 16 + c) * 72 + k2 * 32 + q * 8]);
    al[k2] = *reinterpret_cast<const bf16x8*>(&Al[(w * 16 + c) * 72 + k2 * 32 + q * 8]);
  }
  #pragma unroll
  for (int nb = 0; nb < 4; nb++) {
    f32x4 acc = {0.f, 0.f, 0.f, 0.f};
    #pragma unroll
    for (int k2 = 0; k2 < 2; k2++) {
      bf16x8 bh_ = *reinterpret_cast<const bf16x8*>(&Bh[(nb * 16 + c) * 72 + k2 * 32 + q * 8]);
      bf16x8 bl_ = *reinterpret_cast<const bf16x8*>(&Bl[(nb * 16 + c) * 72 + k2 * 32 + q * 8]);
      acc = MFMA16(ah[k2], bh_, acc);
      acc = MFMA16(ah[k2], bl_, acc);
      acc = MFMA16(al[k2], bh_, acc);
    }
    out[nb] = acc;
  }
}

__global__ __launch_bounds__(256) void ns_inverse_kernel(
    const float* __restrict__ K2, const float* __restrict__ cs,
    float* __restrict__ Vi)
{
  __shared__ u16 K2h[64 * 72], K2l[64 * 72];   // K2, A-form [m][k]
  __shared__ u16 VAh[64 * 72], VAl[64 * 72];   // V,  A-form [m][k]
  __shared__ u16 VTh[64 * 72], VTl[64 * 72];   // V^T, B-form [n][k]
  __shared__ u16 KVh[64 * 72], KVl[64 * 72];   // KV, A-form
  __shared__ u16 Th [64 * 72], Tl [64 * 72];   // (cI - X)^T, B-form
  __shared__ float red[256];
  const int t = threadIdx.x, bh = blockIdx.x;
  const int w = t >> 6, lane = t & 63, q = lane >> 4, c = lane & 15;

  float m = -1e30f;
  for (int i = t; i < BH * LM; i += 256) m = fmaxf(m, cs[i]);
  red[t] = m;
  __syncthreads();
  for (int off = 128; off; off >>= 1) {
    if (t < off) red[t] = fmaxf(red[t], red[t + off]);
    __syncthreads();
  }
  const float ginv = 1.0f / red[0];
  __syncthreads();

  {
    const int r = t >> 2, cb = (t & 3) << 4;
    #pragma unroll
    for (int i = 0; i < 16; i++) {
      float v = K2[((size_t)bh * LM + r) * LM + cb + i];
      u16 h1 = f2bf(v);
      K2h[r * 72 + cb + i] = h1;
      K2l[r * 72 + cb + i] = f2bf(v - bf2f(h1));
      float sv = v * ginv;
      u16 h2 = f2bf(sv);
      u16 l2 = f2bf(sv - bf2f(h2));
      VTh[r * 72 + cb + i] = h2;
      VTl[r * 72 + cb + i] = l2;
      VAh[(cb + i) * 72 + r] = h2;
      VAl[(cb + i) * 72 + r] = l2;
    }
  }
  __syncthreads();

  f32x4 o[4];
  for (int it = 0; it < 6; it++) {
    mm_split(K2h, K2l, VTh, VTl, w, lane, o);
    __syncthreads();
    #pragma unroll
    for (int nb = 0; nb < 4; nb++)
      #pragma unroll
      for (int i = 0; i < 4; i++) {
        const int row = w * 16 + q * 4 + i, col = nb * 16 + c;
        const float v = o[nb][i];
        const u16 h1 = f2bf(v);
        KVh[row * 72 + col] = h1;
        KVl[row * 72 + col] = f2bf(v - bf2f(h1));
        const float tv = (row == col ? 7.0f : 0.0f) - v;
        const u16 h2 = f2bf(tv);
        Th[col * 72 + row] = h2;
        Tl[col * 72 + row] = f2bf(tv - bf2f(h2));
      }
    __syncthreads();
    mm_split(KVh, KVl, Th, Tl, w, lane, o);
    __syncthreads();
    #pragma unroll
    for (int nb = 0; nb < 4; nb++)
      #pragma unroll
      for (int i = 0; i < 4; i++) {
        const int row = w * 16 + q * 4 + i, col = nb * 16 + c;
        const float tv = (row == col ? 15.0f : 0.0f) - o[nb][i];
        const u16 h2 = f2bf(tv);
        Th[col * 72 + row] = h2;
        Tl[col * 72 + row] = f2bf(tv - bf2f(h2));
      }
    __syncthreads();
    mm_split(KVh, KVl, Th, Tl, w, lane, o);
    __syncthreads();
    #pragma unroll
    for (int nb = 0; nb < 4; nb++)
      #pragma unroll
      for (int i = 0; i < 4; i++) {
        const int row = w * 16 + q * 4 + i, col = nb * 16 + c;
        const float tv = (row == col ? 13.0f : 0.0f) - o[nb][i];
        const u16 h2 = f2bf(tv);
        Th[col * 72 + row] = h2;
        Tl[col * 72 + row] = f2bf(tv - bf2f(h2));
      }
    __syncthreads();
    mm_split(VAh, VAl, Th, Tl, w, lane, o);
    __syncthreads();
    #pragma unroll
    for (int nb = 0; nb < 4; nb++)
      #pragma unroll
      for (int i = 0; i < 4; i++) {
        const int row = w * 16 + q * 4 + i, col = nb * 16 + c;
        const float v = 0.25f * o[nb][i];
        const u16 h1 = f2bf(v);
        const u16 l1 = f2bf(v - bf2f(h1));
        VAh[row * 72 + col] = h1;
        VAl[row * 72 + col] = l1;
        VTh[col * 72 + row] = h1;
        VTl[col * 72 + row] = l1;
        if (it == 5) Vi[((size_t)bh * LM + row) * LM + col] = v;
      }
    __syncthreads();
  }
}

// ------------------------------------------------------------- MFMA kernel_3 @ v (split-K partials) v2
__global__ __launch_bounds__(256) void k3v_kernel(
    const u16* __restrict__ qLb, const u16* __restrict__ Kb, const u16* __restrict__ VbT,
    float* __restrict__ pnum, float* __restrict__ pden)
{
  __shared__ u16 Ks[64 * 72], Vs[2][64 * 72], Ps[64 * 72];
  __shared__ float denL[256];
  const int t = threadIdx.x, ch = blockIdx.x, bh = blockIdx.y;
  const int w = t >> 6, lane = t & 63, q = lane >> 4, c = lane & 15;
  const int sr = t >> 2, sp = (t & 3) * 16;

  bf16x8 aq[4][2];
  #pragma unroll
  for (int mi = 0; mi < 4; mi++)
    #pragma unroll
    for (int k2 = 0; k2 < 2; k2++)
      aq[mi][k2] = *reinterpret_cast<const bf16x8*>(
          &qLb[((size_t)bh * LM + mi * 16 + c) * HD + k2 * 32 + q * 8]);

  f32x4 z4 = {0.f, 0.f, 0.f, 0.f};
  f32x4 nacc[4];
  #pragma unroll
  for (int mi = 0; mi < 4; mi++) nacc[mi] = z4;
  float denr[16] = {};

  // prologue loads (sub 0)
  int4 kr0, kr1, vr0, vr1;
  {
    const int s0 = ch * CHS;
    const u16* kp = &Kb[((size_t)bh * SEQL + s0 + sr) * HD + sp];
    const u16* vp = &VbT[((size_t)(bh * HD + sr)) * SEQL + s0 + sp];
    kr0 = *reinterpret_cast<const int4*>(kp);
    kr1 = *reinterpret_cast<const int4*>(kp + 8);
    vr0 = *reinterpret_cast<const int4*>(vp);
    vr1 = *reinterpret_cast<const int4*>(vp + 8);
  }

  for (int sub = 0; sub < 8; sub++) {
    const int cur = sub & 1;
    *reinterpret_cast<int4*>(&Ks[sr * 72 + sp])     = kr0;
    *reinterpret_cast<int4*>(&Ks[sr * 72 + sp + 8]) = kr1;
    *reinterpret_cast<int4*>(&Vs[cur][sr * 72 + sp])     = vr0;
    *reinterpret_cast<int4*>(&Vs[cur][sr * 72 + sp + 8]) = vr1;
    __syncthreads();
    f32x4 sacc[4];
    #pragma unroll
    for (int mi = 0; mi < 4; mi++) sacc[mi] = z4;
    bf16x8 bk0 = *reinterpret_cast<const bf16x8*>(&Ks[(w * 16 + c) * 72 + q * 8]);
    bf16x8 bk1 = *reinterpret_cast<const bf16x8*>(&Ks[(w * 16 + c) * 72 + 32 + q * 8]);
    #pragma unroll
    for (int mi = 0; mi < 4; mi++) {
      sacc[mi] = MFMA16(aq[mi][0], bk0, sacc[mi]);
      sacc[mi] = MFMA16(aq[mi][1], bk1, sacc[mi]);
    }
    #pragma unroll
    for (int mi = 0; mi < 4; mi++)
      #pragma unroll
      for (int i = 0; i < 4; i++) {
        float p = __expf(sacc[mi][i]);
        denr[mi * 4 + i] += p;
        Ps[(mi * 16 + q * 4 + i) * 72 + w * 16 + c] = f2bf(p);
      }
    __syncthreads();
    if (sub < 7) {
      const int s1 = ch * CHS + (sub + 1) * 64;
      const u16* kp = &Kb[((size_t)bh * SEQL + s1 + sr) * HD + sp];
      const u16* vp = &VbT[((size_t)(bh * HD + sr)) * SEQL + s1 + sp];
      kr0 = *reinterpret_cast<const int4*>(kp);
      kr1 = *reinterpret_cast<const int4*>(kp + 8);
      vr0 = *reinterpret_cast<const int4*>(vp);
      vr1 = *reinterpret_cast<const int4*>(vp + 8);
    }
    #pragma unroll
    for (int k2 = 0; k2 < 2; k2++) {
      bf16x8 bv_ = *reinterpret_cast<const bf16x8*>(&Vs[cur][(w * 16 + c) * 72 + k2 * 32 + q * 8]);
      #pragma unroll
      for (int mi = 0; mi < 4; mi++) {
        bf16x8 ap = *reinterpret_cast<const bf16x8*>(&Ps[(mi * 16 + c) * 72 + k2 * 32 + q * 8]);
        nacc[mi] = MFMA16(ap, bv_, nacc[mi]);
      }
    }
  }
  #pragma unroll
  for (int mi = 0; mi < 4; mi++)
    #pragma unroll
    for (int i = 0; i < 4; i++)
      pnum[(((size_t)bh * NCH + ch) * LM + mi * 16 + q * 4 + i) * HD + w * 16 + c] = nacc[mi][i];
  #pragma unroll
  for (int v = 0; v < 16; v++) {
    denr[v] += __shfl_xor(denr[v], 1);
    denr[v] += __shfl_xor(denr[v], 2);
    denr[v] += __shfl_xor(denr[v], 4);
    denr[v] += __shfl_xor(denr[v], 8);
  }
  if (c == 0) {
    #pragma unroll
    for (int mi = 0; mi < 4; mi++)
      #pragma unroll
      for (int i = 0; i < 4; i++)
        denL[w * 64 + mi * 16 + q * 4 + i] = denr[mi * 4 + i];
  }
  __syncthreads();
  if (t < 64)
    pden[((size_t)bh * NCH + ch) * LM + t] = denL[t] + denL[64 + t] + denL[128 + t] + denL[192 + t];
}

// ------------------------------------------------------------- reduce partials; W2T = (Vi @ normalize(k3 v))^T bf16
__global__ __launch_bounds__(256) void k3v_w2_kernel(
    const float* __restrict__ pnum, const float* __restrict__ pden,
    const float* __restrict__ Vi, u16* __restrict__ W2T)
{
  __shared__ float Vs[64 * 65], Ms[64 * 65], den[64];
  const int t = threadIdx.x, bh = blockIdx.x;
  const int r = t >> 2, cb = (t & 3) << 4;
  #pragma unroll
  for (int i = 0; i < 16; i++) Vs[r * 65 + cb + i] = Vi[((size_t)bh * LM + r) * LM + cb + i];
  float acc[16] = {};
  for (int ch = 0; ch < NCH; ch++) {
    const float* p = pnum + (((size_t)bh * NCH + ch) * LM + r) * HD + cb;
    #pragma unroll
    for (int i = 0; i < 16; i++) acc[i] += p[i];
  }
  if ((t & 3) == 0) {
    float d = 0.f;
    for (int ch = 0; ch < NCH; ch++) d += pden[((size_t)bh * NCH + ch) * LM + r];
    den[r] = d;
  }
  __syncthreads();
  const float dinv = 1.0f / den[r];
  #pragma unroll
  for (int i = 0; i < 16; i++) Ms[r * 65 + cb + i] = acc[i] * dinv;
  __syncthreads();
  float o[16] = {};
  for (int k = 0; k < 64; k++) {
    float a = Vs[r * 65 + k];
    #pragma unroll
    for (int i = 0; i < 16; i++) o[i] = fmaf(a, Ms[k * 65 + cb + i], o[i]);
  }
  #pragma unroll
  for (int i = 0; i < 16; i++)
    W2T[((size_t)bh * HD + cb + i) * LM + r] = f2bf(o[i]);
}

// ------------------------------------------------------------- MFMA kernel_1 softmax @ W2
__global__ __launch_bounds__(256) void final_kernel(
    const u16* __restrict__ Qb, const u16* __restrict__ kLb, const u16* __restrict__ W2T,
    u16* __restrict__ pre)
{
  __shared__ u16 Ps[64 * 72];
  __shared__ float mxL[256], smL[256];
  const int t = threadIdx.x, st = blockIdx.x, bh = blockIdx.y;
  const int w = t >> 6, lane = t & 63, q = lane >> 4, c = lane & 15;
  const int sb = st * 64;

  bf16x8 aq[4][2], bkL[2], bw2[2];
  #pragma unroll
  for (int mi = 0; mi < 4; mi++)
    #pragma unroll
    for (int k2 = 0; k2 < 2; k2++)
      aq[mi][k2] = *reinterpret_cast<const bf16x8*>(
          &Qb[((size_t)bh * SEQL + sb + mi * 16 + c) * HD + k2 * 32 + q * 8]);
  #pragma unroll
  for (int k2 = 0; k2 < 2; k2++) {
    bkL[k2] = *reinterpret_cast<const bf16x8*>(
        &kLb[((size_t)bh * LM + w * 16 + c) * HD + k2 * 32 + q * 8]);
    bw2[k2] = *reinterpret_cast<const bf16x8*>(
        &W2T[((size_t)bh * HD + w * 16 + c) * LM + k2 * 32 + q * 8]);
  }

  f32x4 z4 = {0.f, 0.f, 0.f, 0.f};
  f32x4 sacc[4];
  #pragma unroll
  for (int mi = 0; mi < 4; mi++) sacc[mi] = z4;
  #pragma unroll
  for (int k2 = 0; k2 < 2; k2++)
    #pragma unroll
    for (int mi = 0; mi < 4; mi++)
      sacc[mi] = MFMA16(aq[mi][k2], bkL[k2], sacc[mi]);

  float mx[16];
  #pragma unroll
  for (int v = 0; v < 16; v++) {
    mx[v] = sacc[v >> 2][v & 3];
    mx[v] = fmaxf(mx[v], __shfl_xor(mx[v], 1));
    mx[v] = fmaxf(mx[v], __shfl_xor(mx[v], 2));
    mx[v] = fmaxf(mx[v], __shfl_xor(mx[v], 4));
    mx[v] = fmaxf(mx[v], __shfl_xor(mx[v], 8));
  }
  if (c == 0) {
    #pragma unroll
    for (int mi = 0; mi < 4; mi++)
      #pragma unroll
      for (int i = 0; i < 4; i++)
        mxL[w * 64 + mi * 16 + q * 4 + i] = mx[mi * 4 + i];
  }
  __syncthreads();
  float p[16], dn[16];
  #pragma unroll
  for (int mi = 0; mi < 4; mi++)
    #pragma unroll
    for (int i = 0; i < 4; i++) {
      int row = mi * 16 + q * 4 + i;
      float M = fmaxf(fmaxf(mxL[row], mxL[64 + row]), fmaxf(mxL[128 + row], mxL[192 + row]));
      float pp = __expf(sacc[mi][i] - M);
      p[mi * 4 + i] = pp;
      dn[mi * 4 + i] = pp;
    }
  #pragma unroll
  for (int v = 0; v < 16; v++) {
    dn[v] += __shfl_xor(dn[v], 1);
    dn[v] += __shfl_xor(dn[v], 2);
    dn[v] += __shfl_xor(dn[v], 4);
    dn[v] += __shfl_xor(dn[v], 8);
  }
  if (c == 0) {
    #pragma unroll
    for (int mi = 0; mi < 4; mi++)
      #pragma unroll
      for (int i = 0; i < 4; i++)
        smL[w * 64 + mi * 16 + q * 4 + i] = dn[mi * 4 + i];
  }
  #pragma unroll
  for (int mi = 0; mi < 4; mi++)
    #pragma unroll
    for (int i = 0; i < 4; i++)
      Ps[(mi * 16 + q * 4 + i) * 72 + w * 16 + c] = f2bf(p[mi * 4 + i]);
  __syncthreads();

  f32x4 oacc[4];
  #pragma unroll
  for (int mi = 0; mi < 4; mi++) oacc[mi] = z4;
  #pragma unroll
  for (int k2 = 0; k2 < 2; k2++)
    #pragma unroll
    for (int mi = 0; mi < 4; mi++) {
      bf16x8 ap = *reinterpret_cast<const bf16x8*>(&Ps[(mi * 16 + c) * 72 + k2 * 32 + q * 8]);
      oacc[mi] = MFMA16(ap, bw2[k2], oacc[mi]);
    }
  #pragma unroll
  for (int mi = 0; mi < 4; mi++)
    #pragma unroll
    for (int i = 0; i < 4; i++) {
      int row = mi * 16 + q * 4 + i;
      float den = smL[row] + smL[64 + row] + smL[128 + row] + smL[192 + row];
      float v = oacc[mi][i] / den;
      pre[((size_t)((bh >> 3) * SEQL + sb + row)) * EMB + (bh & 7) * HD + w * 16 + c] = f2bf(v);
    }
}

// ------------------------------------------------------------- MFMA out = pre @ Wo + bo v2
__global__ __launch_bounds__(256, 2) void out_proj_kernel(
    const u16* __restrict__ pre, const u16* __restrict__ WoT, const void* bo,
    const int* flag, void* out)
{
  __shared__ u16 As[2 * 128 * 64];   // linear rows, unit-swizzled cols
  __shared__ u16 Bs[2 * 128 * 64];
  const int t = threadIdx.x;
  const int m0 = blockIdx.x * 128, n0 = blockIdx.y * 128;
  const int isf32 = flag[0];
  const int w = t >> 6, lane = t & 63, q = lane >> 4, c = lane & 15;
  const int wm = (w >> 1) * 64, wn = (w & 1) * 64;
  const int row8 = lane >> 3;
  const int colsw = ((lane & 7) ^ row8) * 8;

  f32x4 acc[4][4];
  f32x4 z4 = {0.f, 0.f, 0.f, 0.f};
  #pragma unroll
  for (int mi = 0; mi < 4; mi++)
    #pragma unroll
    for (int ni = 0; ni < 4; ni++) acc[mi][ni] = z4;

  // prologue: tile 0
  #pragma unroll
  for (int u = 0; u < 4; u++) {
    int chA = u * 4 + w;
    async16(&pre[(size_t)(m0 + chA * 8 + row8) * EMB + 0 + colsw], &As[chA * 512]);
    async16(&WoT[(size_t)(n0 + chA * 8 + row8) * EMB + 0 + colsw], &Bs[chA * 512]);
  }
  __syncthreads();

  for (int tt = 0; tt < 8; tt++) {
    const int cur = tt & 1;
    if (tt < 7) {
      const int k1 = (tt + 1) * 64;
      #pragma unroll
      for (int u = 0; u < 4; u++) {
        int chA = u * 4 + w;
        async16(&pre[(size_t)(m0 + chA * 8 + row8) * EMB + k1 + colsw],
                &As[(cur ^ 1) * 8192 + chA * 512]);
        async16(&WoT[(size_t)(n0 + chA * 8 + row8) * EMB + k1 + colsw],
                &Bs[(cur ^ 1) * 8192 + chA * 512]);
      }
    }
    #pragma unroll
    for (int kk = 0; kk < 64; kk += 32) {
      const int u0 = ((((kk >> 3) + q) ^ (c & 7))) * 8;
      bf16x8 af[4], bfv[4];
      #pragma unroll
      for (int mi = 0; mi < 4; mi++)
        af[mi] = *reinterpret_cast<const bf16x8*>(&As[cur * 8192 + (wm + mi * 16 + c) * 64 + u0]);
      #pragma unroll
      for (int ni = 0; ni < 4; ni++)
        bfv[ni] = *reinterpret_cast<const bf16x8*>(&Bs[cur * 8192 + (wn + ni * 16 + c) * 64 + u0]);
      #pragma unroll
      for (int mi = 0; mi < 4; mi++)
        #pragma unroll
        for (int ni = 0; ni < 4; ni++)
          acc[mi][ni] = MFMA16(af[mi], bfv[ni], acc[mi][ni]);
    }
    __syncthreads();
  }
  float bb[4];
  #pragma unroll
  for (int ni = 0; ni < 4; ni++) bb[ni] = load1_any(bo, n0 + wn + ni * 16 + c, isf32);
  #pragma unroll
  for (int mi = 0; mi < 4; mi++)
    #pragma unroll
    for (int i = 0; i < 4; i++) {
      int m = m0 + wm + mi * 16 + q * 4 + i;
      #pragma unroll
      for (int ni = 0; ni < 4; ni++) {
        int n = n0 + wn + ni * 16 + c;
        float v = acc[mi][ni][i] + bb[ni];
        if (isf32) ((float*)out)[(size_t)m * EMB + n] = v;
        else       ((u16*)out)[(size_t)m * EMB + n] = f2bf(v);
      }
    }
}

// ------------------------------------------------------------- launch
extern "C" void kernel_launch(void* const* d_in, const int* in_sizes, int n_in,
                              void* d_out, int out_size, void* d_ws, size_t ws_size,
                              hipStream_t stream)
{
  (void)in_sizes; (void)n_in; (void)out_size; (void)ws_size;
  const void* x  = d_in[0];
  const void* Wq = d_in[1];
  const void* bq = d_in[2];
  const void* Wk = d_in[3];
  const void* bk = d_in[4];
  const void* Wv = d_in[5];
  const void* bv = d_in[6];
  const void* Wo = d_in[7];
  const void* bo = d_in[8];

  float* ws = (float*)d_ws;
  int*   flag  = (int*)ws;                         // 64 floats
  float* xmean = ws + 64;                          // 131072
  float* qL    = xmean + 131072;                   // 131072
  float* kL    = qL + 131072;                      // 131072
  float* K2    = kL + 131072;                      // 131072
  float* cs    = K2 + 131072;                      // 2048
  float* Vi    = cs + 2048;                        // 131072
  float* pnum  = Vi + 131072;                      // 2097152
  float* pden  = pnum + 2097152;                   // 32768
  u16* WqT = (u16*)(pden + 32768);                 // 262144 u16 each
  u16* WkT = WqT + 262144;
  u16* WvT = WkT + 262144;
  u16* WoT = WvT + 262144;
  u16* qLb = WoT + 262144;                         // 131072
  u16* kLb = qLb + 131072;                         // 131072
  u16* W2T = kLb + 131072;                         // 131072
  u16* Qb  = W2T + 131072;                         // 16777216
  u16* Kb  = Qb + 16777216;                        // 16777216
  u16* VbT = Kb + 16777216;                        // 16777216
  u16* xb16 = VbT + 16777216;                      // 16777216 (x as bf16, 32MB)
  u16* pre = Kb;      // alias: Kb dead after k3v_kernel; final runs after k3v_w2
  float* xpart = pnum;  // alias: 2048*512 floats = 4MB; dead before k3v writes pnum

  probe_kernel<<<1, 256, 0, stream>>>(x, flag);
  prep_wt_kernel<<<256, 256, 0, stream>>>(Wq, Wk, Wv, Wo, flag, WqT, WkT, WvT, WoT);
  xpart_kernel<<<2048, 256, 0, stream>>>(x, flag, xpart, xb16);
  xmean_reduce_kernel<<<256, 256, 0, stream>>>(xpart, xmean);
  lm_proj_kernel<<<dim3(4, 8, 2), 256, 0, stream>>>(xmean, Wq, bq, Wk, bk, flag, qL, kL, qLb, kLb);
  proj_qkv_fused_kernel<<<dim3(2048), 256, 0, stream>>>(
      x, xb16, WqT, WkT, WvT, bq, bk, bv, flag, Qb, Kb, VbT);
  k2_softmax_kernel<<<BH, 256, 0, stream>>>(qL, kL, K2, cs);
  ns_inverse_kernel<<<BH, 256, 0, stream>>>(K2, cs, Vi);
  k3v_kernel<<<dim3(NCH, BH), 256, 0, stream>>>(qLb, Kb, VbT, pnum, pden);
  k3v_w2_kernel<<<BH, 256, 0, stream>>>(pnum, pden, Vi, W2T);
  final_kernel<<<dim3(SEQL / 64, BH), 256, 0, stream>>>(Qb, kLb, W2T, pre);
  out_proj_kernel<<<dim3(256, 4), 256, 0, stream>>>(pre, WoT, bo, flag, d_out);
}